// Round 15
// baseline (335.408 us; speedup 1.0000x reference)
//
#include <hip/hip_runtime.h>
#include <stdint.h>

#define DEVFN __device__ __forceinline__

typedef unsigned short u16;
typedef short bf16x8 __attribute__((ext_vector_type(8)));
typedef float f32x4 __attribute__((ext_vector_type(4)));

constexpr int BB = 8, QQ = 300, CC = 300, NN = 300, DD = 256;
constexpr int WHX = 9216, BQ = 2400, SIMW = 600;
constexpr int QP = 320;
constexpr int CP = 304;   // padded C rows (19 MFMA tiles; rows 300..303 zero)
constexpr int KP = 96;
constexpr int NP = 416;
constexpr int CELLCAP = 300;

// ---------------- workspace layout (float units) ----------------
constexpr size_t F_SIMS   = 0;
constexpr size_t F_GTSIM  = F_SIMS   + (size_t)BQ*SIMW;
constexpr size_t F_MM     = F_GTSIM  + (size_t)NN*CC;
constexpr size_t F_SCORE  = F_MM     + (size_t)NN*NN;
constexpr size_t F_BBOX   = F_SCORE  + BQ;
constexpr size_t F_TB     = F_BBOX   + (size_t)BQ*4;
constexpr size_t F_SB     = F_TB     + (size_t)NN*4;
constexpr size_t F_SAREA  = F_SB     + (size_t)BQ*4;
constexpr size_t F_KB     = F_SAREA  + BQ;
constexpr size_t F_ROWSUM = F_KB     + (size_t)BQ*4;
constexpr size_t F_OE     = F_ROWSUM + NN;                     // ---- zeroed zone
constexpr size_t F_GSEL   = F_OE     + (size_t)NN*DD;
constexpr size_t F_MSUM   = F_GSEL   + (size_t)NN*4;
constexpr size_t F_STGT   = F_MSUM   + NN;
constexpr size_t F_SC     = F_STGT   + 8;
constexpr size_t F_CNT    = F_SC     + 16;
constexpr size_t F_ACCEND = F_CNT    + BQ;                     // ---- end zeroed zone
constexpr size_t F_ORDER  = F_ACCEND;
constexpr size_t F_NMSIDX = F_ORDER  + BQ;
constexpr size_t F_SEL2   = F_NMSIDX + BQ;
constexpr size_t F_BSTART = F_SEL2   + NN;
constexpr size_t F_KINT   = F_BSTART + 16;
constexpr size_t F_CLS    = F_KINT   + 4;
constexpr size_t F_KEEPF  = F_CLS    + BQ;
constexpr size_t F_LIST   = F_KEEPF  + BQ;
constexpr size_t F_S2T    = F_LIST   + (size_t)BQ*CELLCAP;     // f32 [300][2400]
constexpr size_t F_SIMTB  = ((F_S2T + (size_t)NN*BQ + 7) & ~(size_t)7);  // u16[8][304][320]
constexpr size_t F_OMT    = F_SIMTB + (size_t)BB*CP*QP/2;
constexpr size_t F_TMT    = F_OMT   + (size_t)WHX*QP/2;
constexpr size_t F_GTP    = F_TMT   + (size_t)WHX*NP/2;        // u16[8][304][96]
constexpr size_t F_TOTAL  = F_GTP   + (size_t)BB*CP*KP/2;

// ---------------- JAX threefry2x32 (partitionable scheme) ----------------
DEVFN uint32_t rotl32(uint32_t v, int r){ return (v << r) | (v >> (32 - r)); }

DEVFN void tf2x32(uint32_t k0, uint32_t k1, uint32_t x0, uint32_t x1,
                  uint32_t& o0, uint32_t& o1){
  uint32_t ks2 = k0 ^ k1 ^ 0x1BD11BDAu;
  x0 += k0; x1 += k1;
#define TFR(r) x0 += x1; x1 = rotl32(x1, r); x1 ^= x0;
  TFR(13) TFR(15) TFR(26) TFR(6)   x0 += k1;  x1 += ks2 + 1u;
  TFR(17) TFR(29) TFR(16) TFR(24)  x0 += ks2; x1 += k0  + 2u;
  TFR(13) TFR(15) TFR(26) TFR(6)   x0 += k0;  x1 += k1  + 3u;
  TFR(17) TFR(29) TFR(16) TFR(24)  x0 += k1;  x1 += ks2 + 4u;
  TFR(13) TFR(15) TFR(26) TFR(6)   x0 += ks2; x1 += k0  + 5u;
#undef TFR
  o0 = x0; o1 = x1;
}

DEVFN void subkey(int i, uint32_t& k0, uint32_t& k1){
  tf2x32(0u, 42u, 0u, (uint32_t)i, k0, k1);
}

DEVFN float gumbel32(uint32_t k0, uint32_t k1, uint32_t idx){
  uint32_t h, l; tf2x32(k0, k1, 0u, idx, h, l);
  uint32_t bits = h ^ l;
  float f = __uint_as_float((bits >> 9) | 0x3F800000u) - 1.0f;
  const float tiny = 1.17549435e-38f;
  float u = fmaxf(tiny, f + tiny);
  return -logf(-logf(u));
}

DEVFN float iou_xyxy(float ax1,float ay1,float ax2,float ay2,
                     float bx1,float by1,float bx2,float by2){
  float aa = (ax2-ax1)*(ay2-ay1);
  float ab = (bx2-bx1)*(by2-by1);
  float lx = fmaxf(ax1,bx1), ly = fmaxf(ay1,by1);
  float rx = fminf(ax2,bx2), ry = fminf(ay2,by2);
  float iw = fmaxf(rx-lx,0.f), ih = fmaxf(ry-ly,0.f);
  float in_ = iw*ih;
  return in_/(aa+ab-in_);
}

DEVFN u16 f2bf(float x){
  uint32_t u = __float_as_uint(x);
  uint32_t r = u + 0x7FFFu + ((u >> 16) & 1u);
  return (u16)(r >> 16);
}

// ---------------- K1: tiled f32 GEMM 64x64 + s2T side-write ----------------
__global__ __launch_bounds__(256) void k_gemm_t(
    const float* __restrict__ pl, const float* __restrict__ ce,
    const float* __restrict__ te, float* __restrict__ sims,
    float* __restrict__ gtsim, float* __restrict__ s2t){
  __shared__ float As[16][64];
  __shared__ float Bs[16][64];
  const int row0 = blockIdx.x * 64, col0 = blockIdx.y * 64;
  const int tid = threadIdx.x;
  const int lrow = tid >> 2, lk0 = (tid & 3) * 4;
  const int tr = tid >> 4, tc = tid & 15;

  float acc[4][4];
  #pragma unroll
  for (int i = 0; i < 4; i++)
    #pragma unroll
    for (int j = 0; j < 4; j++) acc[i][j] = 0.f;

  const float4 z4 = {0.f,0.f,0.f,0.f};
  const int grow = row0 + lrow;
  const int gcol = col0 + lrow;
  const float* arow = nullptr;
  if (grow < 2400) arow = pl + (size_t)grow * DD;
  else if (grow < 2700) arow = te + (size_t)(grow - 2400) * DD;
  const float* brow = nullptr;
  if (gcol < 300) brow = ce + (size_t)gcol * DD;
  else if (gcol < 600) brow = te + (size_t)(gcol - 300) * DD;

  float4 av = arow ? *(const float4*)(arow + lk0) : z4;
  float4 bv = brow ? *(const float4*)(brow + lk0) : z4;

  for (int step = 0; step < 16; step++){
    __syncthreads();
    #pragma unroll
    for (int j = 0; j < 4; j++){
      As[lk0 + j][lrow] = ((const float*)&av)[j];
      Bs[lk0 + j][lrow] = ((const float*)&bv)[j];
    }
    __syncthreads();
    if (step + 1 < 16){
      const int k0 = (step + 1) * 16;
      av = arow ? *(const float4*)(arow + k0 + lk0) : z4;
      bv = brow ? *(const float4*)(brow + k0 + lk0) : z4;
    }
    #pragma unroll
    for (int kk = 0; kk < 16; kk++){
      float4 a4 = *(const float4*)&As[kk][tr*4];
      float4 b4 = *(const float4*)&Bs[kk][tc*4];
      float a[4] = {a4.x,a4.y,a4.z,a4.w};
      float b[4] = {b4.x,b4.y,b4.z,b4.w};
      #pragma unroll
      for (int i = 0; i < 4; i++)
        #pragma unroll
        for (int j = 0; j < 4; j++)
          acc[i][j] = fmaf(a[i], b[j], acc[i][j]);
    }
  }

  #pragma unroll
  for (int i = 0; i < 4; i++){
    const int r = row0 + tr*4 + i;
    const int c0 = col0 + tc*4;
    if (r < 2400){
      if (c0 < 600){
        float4 o0 = {acc[i][0],acc[i][1],acc[i][2],acc[i][3]};
        *(float4*)(sims + (size_t)r*SIMW + c0) = o0;
        if (c0 >= 300){
          #pragma unroll
          for (int j = 0; j < 4; j++)
            s2t[(size_t)(c0 + j - 300)*BQ + r] = acc[i][j];
        }
      }
    } else if (r < 2700){
      const int n = r - 2400;
      #pragma unroll
      for (int j = 0; j < 4; j++){
        int c = c0 + j;
        if (c < 300) gtsim[(size_t)n*CC + c] = acc[i][j];
      }
    }
  }
}

// ---------------- K2: per-bq scores/argmax(g0)/boxes/cls; tb rows; gtsim rowsums ----------------
__global__ __launch_bounds__(256) void k_post(
    const float* __restrict__ sims, const float* __restrict__ pb,
    const float* __restrict__ tbb, const int* __restrict__ tids,
    const int* __restrict__ bidx, const float* __restrict__ gtsim,
    float* __restrict__ score, float* __restrict__ bbox,
    float* __restrict__ tb, float* __restrict__ rowsum,
    int* __restrict__ clsout){
  int bq = blockIdx.x, tid = threadIdx.x;
  __shared__ float sv[256];
  __shared__ int   si[256];
  const int i2 = tid + 256;
  float v1 = (tid < CC) ? sims[(size_t)bq*SIMW + tid] : -INFINITY;
  float v2 = (i2  < CC) ? sims[(size_t)bq*SIMW + i2]  : -INFINITY;
  sv[tid] = fmaxf(v1, v2); __syncthreads();
  for (int s = 128; s > 0; s >>= 1){ if (tid < s) sv[tid] = fmaxf(sv[tid], sv[tid+s]); __syncthreads(); }
  if (tid == 0) score[bq] = sv[0];
  __syncthreads();
  uint32_t gk0, gk1; subkey(0, gk0, gk1);
  float y1 = (tid < CC) ? v1 + gumbel32(gk0, gk1, (uint32_t)(bq*CC + tid)) : -INFINITY;
  float y2 = (i2  < CC) ? v2 + gumbel32(gk0, gk1, (uint32_t)(bq*CC + i2))  : -INFINITY;
  float ym; int yi;
  if (y2 > y1){ ym = y2; yi = i2; } else { ym = y1; yi = tid; }
  sv[tid] = ym; si[tid] = yi; __syncthreads();
  for (int s = 128; s > 0; s >>= 1){
    if (tid < s){
      float ov = sv[tid+s]; int oi = si[tid+s];
      if (ov > sv[tid] || (ov == sv[tid] && oi < si[tid])){ sv[tid] = ov; si[tid] = oi; }
    }
    __syncthreads();
  }
  if (tid == 0){
    int cls = si[0];
    clsout[bq] = cls;
    float ox = 224.0f * (float)cls;
    float oy = 224.0f * (float)(bq / QQ);
    float cx = pb[bq*4+0], cy = pb[bq*4+1], ww = pb[bq*4+2], hh = pb[bq*4+3];
    bbox[bq*4+0] = cx - 0.5f*ww + ox;
    bbox[bq*4+1] = cy - 0.5f*hh + oy;
    bbox[bq*4+2] = cx + 0.5f*ww + ox;
    bbox[bq*4+3] = cy + 0.5f*hh + oy;
  }
  if (bq < NN){
    __syncthreads();
    float r1 = (tid < CC) ? gtsim[(size_t)bq*CC + tid] : 0.f;
    float r2 = (i2  < CC) ? gtsim[(size_t)bq*CC + i2]  : 0.f;
    sv[tid] = r1 + r2; __syncthreads();
    for (int s = 128; s > 0; s >>= 1){ if (tid < s) sv[tid] += sv[tid+s]; __syncthreads(); }
    if (tid == 0) rowsum[bq] = sv[0];
    if (tid == 1){
      float gx = 224.0f * (float)tids[bq], gy = 224.0f * (float)bidx[bq];
      float cx = tbb[bq*4+0], cy = tbb[bq*4+1], ww = tbb[bq*4+2], hh = tbb[bq*4+3];
      tb[bq*4+0] = cx - 0.5f*ww + gx;
      tb[bq*4+1] = cy - 0.5f*hh + gy;
      tb[bq*4+2] = cx + 0.5f*ww + gx;
      tb[bq*4+3] = cy + 0.5f*hh + gy;
    }
  }
}

// ---------------- K3: fused rank + gather + bucket ----------------
__global__ __launch_bounds__(256) void k_rankgather(
    const float* __restrict__ score, const float* __restrict__ bbox,
    const int* __restrict__ cls, const int* __restrict__ bidx,
    int* __restrict__ order, float* __restrict__ sb,
    int* __restrict__ bstart, int* __restrict__ cnt,
    int* __restrict__ list){
  const int t = blockIdx.x;
  const int tid = threadIdx.x;
  const float st = score[t];
  int c = 0;
  for (int j = tid; j < BQ; j += 256){
    float sj = score[j];
    c += (sj > st) || (sj == st && j < t);
  }
  __shared__ int red[256];
  red[tid] = c; __syncthreads();
  for (int s = 128; s > 0; s >>= 1){
    if (tid < s) red[tid] += red[tid+s];
    __syncthreads();
  }
  if (tid == 0){
    int r = red[0];
    order[r] = t;
    float x1 = bbox[t*4+0], y1 = bbox[t*4+1], x2 = bbox[t*4+2], y2 = bbox[t*4+3];
    sb[r*4+0] = x1; sb[r*4+1] = y1; sb[r*4+2] = x2; sb[r*4+3] = y2;
    int key = (t / QQ) * CC + cls[t];
    int slot = atomicAdd(&cnt[key], 1);
    list[(size_t)key*CELLCAP + slot] = r;
  }
  if (t == 0 && tid >= 32 && tid < 41){
    int b = tid - 32, cb = 0;
    for (int n = 0; n < NN; n++) cb += (bidx[n] < b);
    bstart[b] = cb;
  }
}

// ---------------- K6': per-cell greedy NMS ----------------
__global__ __launch_bounds__(256) void k_cellnms(
    const float* __restrict__ sb, const int* __restrict__ cnt,
    const int* __restrict__ list, int* __restrict__ keepf){
  int key = blockIdx.x*256 + threadIdx.x;
  if (key >= BB*CC) return;
  int m = cnt[key];
  if (m <= 0) return;
  const int* lst = list + (size_t)key*CELLCAP;
  unsigned long long keptmask = 0ull;
  int prevp = -1;
  for (int a = 0; a < m; a++){
    int pa = 0x7fffffff;
    for (int j = 0; j < m; j++){
      int pj = lst[j];
      if (pj > prevp && pj < pa) pa = pj;
    }
    prevp = pa;
    float4 A = ((const float4*)sb)[pa];
    float areaA = (A.z-A.x)*(A.w-A.y);
    bool kept = true;
    int pbprev = -1;
    for (int b2 = 0; b2 < a; b2++){
      int pb = 0x7fffffff;
      for (int j = 0; j < m; j++){
        int pj = lst[j];
        if (pj > pbprev && pj < pb) pb = pj;
      }
      pbprev = pb;
      bool keptb = (m <= 64) ? (((keptmask >> b2) & 1ull) != 0ull) : (keepf[pb] != 0);
      if (!keptb) continue;
      float4 B = ((const float4*)sb)[pb];
      float areaB = (B.z-B.x)*(B.w-B.y);
      float lx = fmaxf(A.x,B.x), ly = fmaxf(A.y,B.y);
      float rx = fminf(A.z,B.z), ry = fminf(A.w,B.w);
      float iw = fmaxf(rx-lx,0.f), ih = fmaxf(ry-ly,0.f);
      float inter = iw*ih;
      if (inter/(areaA + areaB - inter) > 0.5f){ kept = false; break; }
    }
    if (m <= 64 && kept) keptmask |= (1ull << a);
    keepf[pa] = kept ? 1 : 0;
  }
}

// ---------------- K7: compact ----------------
__global__ __launch_bounds__(256) void k_compact(
    const int* __restrict__ keepflag, const int* __restrict__ order,
    const float* __restrict__ sb, int* __restrict__ nmsidx,
    float* __restrict__ kb, int* __restrict__ kint){
  __shared__ int csum[256];
  int tid = threadIdx.x;
  int p0 = tid*10;
  int keepf[10];
  int cnt = 0;
  #pragma unroll
  for (int d = 0; d < 10; d++){
    int p = p0 + d;
    int k = 0;
    if (p < BQ) k = keepflag[p];
    keepf[d] = k; cnt += k;
  }
  csum[tid] = cnt; __syncthreads();
  for (int s = 1; s < 256; s <<= 1){
    int add = (tid >= s) ? csum[tid - s] : 0;
    __syncthreads();
    csum[tid] += add;
    __syncthreads();
  }
  int pos = csum[tid] - cnt;
  #pragma unroll
  for (int d = 0; d < 10; d++){
    if (keepf[d]){
      int p = p0 + d;
      nmsidx[pos] = order[p];
      ((float4*)kb)[pos] = ((const float4*)sb)[p];
      pos++;
    }
  }
  if (tid == 255) kint[0] = csum[255];
}

// ---------------- K8: per-kept-box scatter ----------------
__global__ __launch_bounds__(512) void k_gtsel(
    const float* __restrict__ kb, const float* __restrict__ tb,
    const int* __restrict__ nmsidx, const float* __restrict__ pl,
    const int* __restrict__ kint, float* __restrict__ gsel,
    float* __restrict__ oe){
  int k = blockIdx.x;
  if (k >= kint[0]) return;
  int tid = threadIdx.x;
  __shared__ float sv[512];
  __shared__ int   si[512];
  float4 a = ((const float4*)kb)[k];
  float iou = -INFINITY;
  if (tid < NN){
    float4 t = ((const float4*)tb)[tid];
    iou = iou_xyxy(a.x,a.y,a.z,a.w, t.x,t.y,t.z,t.w);
    if (iou != iou) iou = 0.f;
  }
  sv[tid] = iou; __syncthreads();
  for (int s = 256; s > 0; s >>= 1){ if (tid < s) sv[tid] = fmaxf(sv[tid], sv[tid+s]); __syncthreads(); }
  float m = sv[0]; __syncthreads();
  float e = (tid < NN) ? expf(iou - m) : 0.f;
  sv[tid] = e; __syncthreads();
  for (int s = 256; s > 0; s >>= 1){ if (tid < s) sv[tid] += sv[tid+s]; __syncthreads(); }
  float S = sv[0]; __syncthreads();
  uint32_t gk0, gk1; subkey(1, gk0, gk1);
  float y = (tid < NN) ? (e / S + gumbel32(gk0, gk1, (uint32_t)(k*NN + tid))) : -INFINITY;
  sv[tid] = y; si[tid] = tid; __syncthreads();
  for (int s = 256; s > 0; s >>= 1){
    if (tid < s){
      float ov = sv[tid+s]; int oi = si[tid+s];
      if (ov > sv[tid] || (ov == sv[tid] && oi < si[tid])){ sv[tid] = ov; si[tid] = oi; }
    }
    __syncthreads();
  }
  int sel = si[0];
  if (tid < 4) atomicAdd(&gsel[sel*4 + tid], ((const float*)&a)[tid]);
  if (tid < DD) atomicAdd(&oe[(size_t)sel*DD + tid], pl[(size_t)nmsidx[k]*DD + tid]);
}

// ---------------- K10: tiled M = te @ oe^T (32x32 tiles) ----------------
__global__ __launch_bounds__(256) void k_m_t(
    const float* __restrict__ te, const float* __restrict__ oe,
    float* __restrict__ M){
  __shared__ float As[16][32];
  __shared__ float Bs[16][32];
  const int row0 = blockIdx.x * 32, col0 = blockIdx.y * 32;
  const int tid = threadIdx.x;
  const int lr = tid >> 3, lk0 = (tid & 7) * 2;
  const int tr = tid >> 4, tc = tid & 15;
  float acc[2][2] = {{0.f,0.f},{0.f,0.f}};
  const float* arow = (row0 + lr < NN) ? te + (size_t)(row0 + lr)*DD : nullptr;
  const float* brow = (col0 + lr < NN) ? oe + (size_t)(col0 + lr)*DD : nullptr;
  for (int step = 0; step < 16; step++){
    const int k0 = step*16;
    float2 a2 = arow ? *(const float2*)(arow + k0 + lk0) : float2{0.f,0.f};
    float2 b2 = brow ? *(const float2*)(brow + k0 + lk0) : float2{0.f,0.f};
    __syncthreads();
    As[lk0][lr] = a2.x; As[lk0+1][lr] = a2.y;
    Bs[lk0][lr] = b2.x; Bs[lk0+1][lr] = b2.y;
    __syncthreads();
    #pragma unroll
    for (int kk = 0; kk < 16; kk++){
      float a0 = As[kk][tr*2], a1 = As[kk][tr*2+1];
      float b0 = Bs[kk][tc*2], b1 = Bs[kk][tc*2+1];
      acc[0][0] = fmaf(a0,b0,acc[0][0]);
      acc[0][1] = fmaf(a0,b1,acc[0][1]);
      acc[1][0] = fmaf(a1,b0,acc[1][0]);
      acc[1][1] = fmaf(a1,b1,acc[1][1]);
    }
  }
  #pragma unroll
  for (int i = 0; i < 2; i++){
    int r = row0 + tr*2 + i;
    if (r >= NN) continue;
    #pragma unroll
    for (int j = 0; j < 2; j++){
      int c = col0 + tc*2 + j;
      if (c < NN) M[(size_t)r*NN + c] = acc[i][j];
    }
  }
}

// ---------------- K11: both cross-entropies ----------------
__global__ __launch_bounds__(64) void k_ce(
    const float* __restrict__ M, float* __restrict__ sc){
  int i = blockIdx.x, lane = threadIdx.x;
  float m = -INFINITY;
  for (int j = lane; j < NN; j += 64) m = fmaxf(m, M[(size_t)i*NN + j]);
  for (int o = 32; o > 0; o >>= 1) m = fmaxf(m, __shfl_xor(m, o));
  float s = 0.f;
  for (int j = lane; j < NN; j += 64) s += expf(M[(size_t)i*NN + j] - m);
  for (int o = 32; o > 0; o >>= 1) s += __shfl_xor(s, o);
  float lr = m + logf(s);
  float m2 = -INFINITY;
  for (int j = lane; j < NN; j += 64) m2 = fmaxf(m2, M[(size_t)j*NN + i]);
  for (int o = 32; o > 0; o >>= 1) m2 = fmaxf(m2, __shfl_xor(m2, o));
  float s2 = 0.f;
  for (int j = lane; j < NN; j += 64) s2 += expf(M[(size_t)j*NN + i] - m2);
  for (int o = 32; o > 0; o >>= 1) s2 += __shfl_xor(s2, o);
  float lc = m2 + logf(s2);
  if (lane == 0){
    float d = M[(size_t)i*NN + i];
    atomicAdd(&sc[0], lr - d);
    atomicAdd(&sc[1], lc - d);
  }
}

// ---------------- K12: sel2 (coalesced via s2T) ----------------
__global__ __launch_bounds__(256) void k_sel2(
    const float* __restrict__ s2t, int* __restrict__ sel2){
  int n = blockIdx.x, tid = threadIdx.x;
  uint32_t gk0, gk1; subkey(2, gk0, gk1);
  float best = -INFINITY; int bi = 0x7fffffff;
  for (int r = tid; r < BQ; r += 256){
    float v = s2t[(size_t)n*BQ + r] + gumbel32(gk0, gk1, (uint32_t)(r*NN + n));
    if (v > best){ best = v; bi = r; }
  }
  __shared__ float sv[256];
  __shared__ int   si[256];
  sv[tid] = best; si[tid] = bi; __syncthreads();
  for (int s = 128; s > 0; s >>= 1){
    if (tid < s){
      float ov = sv[tid+s]; int oi = si[tid+s];
      if (ov > sv[tid] || (ov == sv[tid] && oi < si[tid])){ sv[tid] = ov; si[tid] = oi; }
    }
    __syncthreads();
  }
  if (tid == 0) sel2[n] = si[0];
}

// ---------------- K_PACK: fused transposes + k_om (5 ranges) ----------------
constexpr int PB_SIMT = 400;                // (10 q) x (5 c) x 8 b
constexpr int PB_OMT  = 1440;               // (10 q) x 144 wh
constexpr int PB_TMT  = 1872;               // (13 n) x 144 wh
constexpr int PB_GTP  = 114;                // 8*304*12 / 256
constexpr int PB_OM   = 2700;               // 300 n x 9 ch
__global__ __launch_bounds__(256) void k_pack(
    const float* __restrict__ sims, const float* __restrict__ pm,
    const float* __restrict__ tm, const float* __restrict__ gtsim,
    const int* __restrict__ sel2, const int* __restrict__ bstart,
    u16* __restrict__ simTb, u16* __restrict__ omT,
    u16* __restrict__ tmT, u16* __restrict__ gtp,
    float* __restrict__ msum, float* __restrict__ sc){
  __shared__ float ld[32][65];
  const int blk = blockIdx.x;
  const int tid = threadIdx.x;

  if (blk < PB_SIMT){
    int bx = blk % 10, by = (blk / 10) % 5, b = blk / 50;
    int q0 = bx*32, c0 = by*64;
    for (int i = tid; i < 32*64; i += 256){
      int qi = i >> 6, ci = i & 63;
      int q = q0 + qi, c = c0 + ci;
      ld[qi][ci] = (q < QQ && c < CC) ? sims[((size_t)b*QQ + q)*SIMW + c] : 0.f;
    }
    __syncthreads();
    int cloc = tid >> 2, j0 = (tid & 3)*8;
    int c = c0 + cloc;
    if (c < CP){
      u16 tmp[8];
      #pragma unroll
      for (int j = 0; j < 8; j++) tmp[j] = f2bf(ld[j0+j][cloc]);
      *(uint4*)(simTb + ((size_t)b*CP + c)*QP + q0 + j0) = *(const uint4*)tmp;
    }
  } else if (blk < PB_SIMT + PB_OMT){
    int r = blk - PB_SIMT;
    int q0 = (r % 10)*32, wh0 = (r / 10)*64;
    for (int i = tid; i < 32*64; i += 256){
      int qi = i >> 6, wi = i & 63;
      int q = q0 + qi;
      ld[qi][wi] = (q < QQ) ? pm[(size_t)sel2[q]*WHX + wh0 + wi] * (1.0f/96.0f) : 0.f;
    }
    __syncthreads();
    int wloc = tid >> 2, j0 = (tid & 3)*8;
    u16 tmp[8];
    #pragma unroll
    for (int j = 0; j < 8; j++) tmp[j] = f2bf(ld[j0+j][wloc]);
    *(uint4*)(omT + (size_t)(wh0+wloc)*QP + q0 + j0) = *(const uint4*)tmp;
  } else if (blk < PB_SIMT + PB_OMT + PB_TMT){
    int r = blk - PB_SIMT - PB_OMT;
    int n0 = (r % 13)*32, wh0 = (r / 13)*64;
    for (int i = tid; i < 32*64; i += 256){
      int ni = i >> 6, wi = i & 63;
      int n = n0 + ni;
      ld[ni][wi] = (n < NN) ? tm[(size_t)n*WHX + wh0 + wi] : 0.f;
    }
    __syncthreads();
    int wloc = tid >> 2, j0 = (tid & 3)*8;
    u16 tmp[8];
    #pragma unroll
    for (int j = 0; j < 8; j++) tmp[j] = f2bf(ld[j0+j][wloc]);
    *(uint4*)(tmT + (size_t)(wh0+wloc)*NP + n0 + j0) = *(const uint4*)tmp;
  } else if (blk < PB_SIMT + PB_OMT + PB_TMT + PB_GTP){
    int g = (blk - PB_SIMT - PB_OMT - PB_TMT)*256 + tid;
    int b = g / (CP*(KP/8));
    int rem = g - b*(CP*(KP/8));
    int c = rem / (KP/8);
    int kg = rem % (KP/8);
    int n0 = bstart[b], n1 = bstart[b+1];
    int kst = n0 & ~7;
    u16 tmp[8];
    #pragma unroll
    for (int j = 0; j < 8; j++){
      int n = kst + kg*8 + j;
      float v = (n >= n0 && n < n1 && c < CC) ? gtsim[(size_t)n*CC + c] : 0.f;
      tmp[j] = f2bf(v);
    }
    *(uint4*)(gtp + ((size_t)b*CP + c)*KP + kg*8) = *(const uint4*)tmp;
  } else {
    int nb = blk - (PB_SIMT + PB_OMT + PB_TMT + PB_GTP);
    int n = nb / 9, ch = nb % 9;
    int c0 = ch*1024 + tid*4;
    const float4 o4 = *(const float4*)(pm + (size_t)sel2[n]*WHX + c0);
    const float4 t4 = *(const float4*)(tm + (size_t)n*WHX + c0);
    float dx = o4.x-t4.x, dy = o4.y-t4.y, dz = o4.z-t4.z, dw = o4.w-t4.w;
    float d2 = dx*dx + dy*dy + dz*dz + dw*dw;
    float ts = t4.x + t4.y + t4.z + t4.w;
    float* r1 = &ld[0][0];
    float* r2 = r1 + 256;
    r1[tid] = d2; r2[tid] = ts; __syncthreads();
    for (int s = 128; s > 0; s >>= 1){
      if (tid < s){ r1[tid] += r1[tid+s]; r2[tid] += r2[tid+s]; }
      __syncthreads();
    }
    if (tid == 0){ atomicAdd(&sc[2], r1[0]); atomicAdd(&msum[n], r2[0]); }
  }
}

// ---------------- K15: MFMA z-GEMM + column softmax + dice (L2-direct, no LDS staging) ----------------
// Per-XCD working set (8 simTb panels + omT/tmT tile slices ~2.5MB) is L2-resident
// under tile-range pinning, so A-fragments are read DIRECTLY from global (L2
// broadcast across the 4 waves). No main-loop barriers, no LDS occupancy cap;
// 19 independent 16B loads per K-step give the ILP. Bit-identical math chain.
__global__ __launch_bounds__(256) void k_zsoft(
    const u16* __restrict__ simTb, const u16* __restrict__ omT,
    const u16* __restrict__ gtp, const u16* __restrict__ tmT,
    const int* __restrict__ bstart, float* __restrict__ sc){
  const int bid = blockIdx.x;
  const int xcd = bid & 7;
  const int r9  = bid >> 3;
  const int tile = xcd * 18 + (r9 % 18);
  const int b    = r9 / 18;
  const int tid = threadIdx.x;
  const int w = tid >> 6, l = tid & 63;
  const int lrow = l & 15, lgrp = l >> 4;
  const int col = tile*64 + w*16 + lrow;

  __shared__ float red[256];

  const u16* Ab = simTb + (size_t)b*CP*QP + (size_t)lrow*QP + lgrp*8;
  const u16* pB = omT + (size_t)col*QP + lgrp*8;

  f32x4 acc[19];
  #pragma unroll
  for (int t = 0; t < 19; t++) acc[t] = (f32x4){0.f,0.f,0.f,0.f};

  for (int ks = 0; ks < 10; ks++){
    const int ko = ks * 32;
    bf16x8 bcur = *(const bf16x8*)(pB + ko);
    #pragma unroll
    for (int t = 0; t < 19; t++){
      bf16x8 af = *(const bf16x8*)(Ab + (size_t)t*16*QP + ko);
      acc[t] = __builtin_amdgcn_mfma_f32_16x16x32_bf16(af, bcur, acc[t], 0, 0, 0);
    }
  }

  float lmax = -INFINITY;
  #pragma unroll
  for (int t = 0; t < 19; t++){
    if (t == 18 && lgrp == 3) continue;
    lmax = fmaxf(lmax, fmaxf(fmaxf(acc[t][0], acc[t][1]), fmaxf(acc[t][2], acc[t][3])));
  }
  lmax = fmaxf(lmax, __shfl_xor(lmax, 16));
  lmax = fmaxf(lmax, __shfl_xor(lmax, 32));
  float ls = 0.f;
  #pragma unroll
  for (int t = 0; t < 19; t++){
    if (t == 18 && lgrp == 3){
      acc[t] = (f32x4){0.f,0.f,0.f,0.f};
      continue;
    }
    float p0 = __expf(acc[t][0] - lmax);
    float p1 = __expf(acc[t][1] - lmax);
    float p2 = __expf(acc[t][2] - lmax);
    float p3 = __expf(acc[t][3] - lmax);
    acc[t][0] = p0; acc[t][1] = p1; acc[t][2] = p2; acc[t][3] = p3;
    ls += p0 + p1 + p2 + p3;
  }
  float S = ls;
  S += __shfl_xor(S, 16);
  S += __shfl_xor(S, 32);
  float inv = 1.f / S;

  const int n0 = bstart[b];
  const int kst = n0 & ~7;
  const u16* tB = tmT + (size_t)col*NP + kst + lgrp*8;
  bf16x8 b2a = *(const bf16x8*)(tB);
  bf16x8 b2b = *(const bf16x8*)(tB + 32);
  bf16x8 b2c = *(const bf16x8*)(tB + 64);
  const u16* A2 = gtp + (size_t)b*CP*KP + (size_t)lrow*KP + lgrp*8;
  float dl = 0.f;
  #pragma unroll
  for (int t = 0; t < 19; t++){
    const u16* ar = A2 + (size_t)t*16*KP;
    f32x4 rr = (f32x4){0.f,0.f,0.f,0.f};
    rr = __builtin_amdgcn_mfma_f32_16x16x32_bf16(*(const bf16x8*)(ar),      b2a, rr, 0, 0, 0);
    rr = __builtin_amdgcn_mfma_f32_16x16x32_bf16(*(const bf16x8*)(ar + 32), b2b, rr, 0, 0, 0);
    rr = __builtin_amdgcn_mfma_f32_16x16x32_bf16(*(const bf16x8*)(ar + 64), b2c, rr, 0, 0, 0);
    dl += acc[t][0]*rr[0] + acc[t][1]*rr[1] + acc[t][2]*rr[2] + acc[t][3]*rr[3];
  }
  dl *= inv;

  red[tid] = dl; __syncthreads();
  for (int s = 128; s > 0; s >>= 1){
    if (tid < s) red[tid] += red[tid+s];
    __syncthreads();
  }
  if (tid == 0) atomicAdd(&sc[5], red[0]);
}

// ---------------- K16: fused gtiou + sumtgt + finalize ----------------
__global__ __launch_bounds__(512) void k_final3(
    const float* __restrict__ gsel, const float* __restrict__ tb,
    const int* __restrict__ bidx, const float* __restrict__ rowsum,
    const float* __restrict__ msum, const float* __restrict__ sc,
    const int* __restrict__ kint, float* __restrict__ out){
  int tid = threadIdx.x;
  __shared__ float s1[512], s2[512];
  __shared__ float stgt[8];
  if (tid < 8) stgt[tid] = 0.f;
  __syncthreads();
  float a1 = 0.f, a2 = 0.f;
  if (tid < NN){
    float4 g = ((const float4*)gsel)[tid];
    float4 t = ((const float4*)tb)[tid];
    float iou = iou_xyxy(g.x,g.y,g.z,g.w, t.x,t.y,t.z,t.w);
    a1 = 1.f - iou;
    a2 = fabsf(g.x-t.x) + fabsf(g.y-t.y) + fabsf(g.z-t.z) + fabsf(g.w-t.w);
    atomicAdd(&stgt[bidx[tid]], rowsum[tid] * msum[tid]);
  }
  s1[tid] = a1; s2[tid] = a2; __syncthreads();
  for (int s = 256; s > 0; s >>= 1){
    if (tid < s){ s1[tid] += s1[tid+s]; s2[tid] += s2[tid+s]; }
    __syncthreads();
  }
  if (tid == 0){
    float K = (float)kint[0];
    float cls = sc[0]/300.f + sc[1]/300.f;
    float stot = sc[5];
    float dice = 0.f;
    for (int b = 0; b < 8; b++) dice += stot / (9216.0f + stgt[b] + 1e-6f);
    dice *= (1.0f/8.0f);
    out[0] = cls;
    out[1] = dice;
    out[2] = (sc[2] / 2764800.0f) / K;
    out[3] = s1[0] / K;
    out[4] = s2[0] / K;
  }
}

// ---------------- launch ----------------
extern "C" void kernel_launch(void* const* d_in, const int* in_sizes, int n_in,
                              void* d_out, int out_size, void* d_ws, size_t ws_size,
                              hipStream_t stream) {
  const float* ce  = (const float*)d_in[0];
  const float* pl  = (const float*)d_in[1];
  const float* pb  = (const float*)d_in[2];
  const float* pm  = (const float*)d_in[3];
  const float* tm  = (const float*)d_in[4];
  const float* te  = (const float*)d_in[5];
  const float* tbb = (const float*)d_in[6];
  const int*  tids = (const int*)d_in[8];
  const int*  bidx = (const int*)d_in[9];
  float* out = (float*)d_out;
  float* w = (float*)d_ws;

  if (ws_size < F_TOTAL * sizeof(float)) return;

  float* SIMS   = w + F_SIMS;
  float* GTSIM  = w + F_GTSIM;
  float* MM     = w + F_MM;
  float* SCORE  = w + F_SCORE;
  float* BBOX   = w + F_BBOX;
  float* TBOX   = w + F_TB;
  float* SB     = w + F_SB;
  float* KB     = w + F_KB;
  float* ROWSUM = w + F_ROWSUM;
  float* OE     = w + F_OE;
  float* GSEL   = w + F_GSEL;
  float* MSUM   = w + F_MSUM;
  float* SC     = w + F_SC;
  float* S2T    = w + F_S2T;
  int*   CNT    = (int*)(w + F_CNT);
  int*   ORDER  = (int*)(w + F_ORDER);
  int*   NMSIDX = (int*)(w + F_NMSIDX);
  int*   SEL2   = (int*)(w + F_SEL2);
  int*   BSTART = (int*)(w + F_BSTART);
  int*   KINT   = (int*)(w + F_KINT);
  int*   CLS    = (int*)(w + F_CLS);
  int*   KEEPF  = (int*)(w + F_KEEPF);
  int*   LIST   = (int*)(w + F_LIST);
  u16* SIMTB = (u16*)(w + F_SIMTB);
  u16* OMT   = (u16*)(w + F_OMT);
  u16* TMT   = (u16*)(w + F_TMT);
  u16* GTP   = (u16*)(w + F_GTP);

  hipMemsetAsync(w + F_OE, 0, (F_ACCEND - F_OE) * sizeof(float), stream);

  k_gemm_t<<<dim3(43, 10), 256, 0, stream>>>(pl, ce, te, SIMS, GTSIM, S2T);
  k_post<<<BQ, 256, 0, stream>>>(SIMS, pb, tbb, tids, bidx, GTSIM, SCORE, BBOX, TBOX, ROWSUM, CLS);
  k_rankgather<<<BQ, 256, 0, stream>>>(SCORE, BBOX, CLS, bidx, ORDER, SB, BSTART, CNT, LIST);
  k_sel2<<<NN, 256, 0, stream>>>(S2T, SEL2);
  k_pack<<<PB_SIMT + PB_OMT + PB_TMT + PB_GTP + PB_OM, 256, 0, stream>>>(
      SIMS, pm, tm, GTSIM, SEL2, BSTART, SIMTB, OMT, TMT, GTP, MSUM, SC);
  k_cellnms<<<(BB*CC + 255)/256, 256, 0, stream>>>(SB, CNT, LIST, KEEPF);
  k_compact<<<1, 256, 0, stream>>>(KEEPF, ORDER, SB, NMSIDX, KB, KINT);
  k_gtsel<<<BQ, 512, 0, stream>>>(KB, TBOX, NMSIDX, pl, KINT, GSEL, OE);
  k_m_t<<<dim3(10, 10), 256, 0, stream>>>(te, OE, MM);
  k_ce<<<NN, 64, 0, stream>>>(MM, SC);
  k_zsoft<<<dim3((WHX/64) * BB), 256, 0, stream>>>(SIMTB, OMT, GTP, TMT, BSTART, SC);
  k_final3<<<1, 512, 0, stream>>>(GSEL, TBOX, bidx, ROWSUM, MSUM, SC, KINT, out);
}

// Round 16
// 239.897 us; speedup vs baseline: 1.3981x; 1.3981x over previous
//
#include <hip/hip_runtime.h>
#include <stdint.h>

#define DEVFN __device__ __forceinline__

typedef unsigned short u16;
typedef short bf16x8 __attribute__((ext_vector_type(8)));
typedef float f32x4 __attribute__((ext_vector_type(4)));

constexpr int BB = 8, QQ = 300, CC = 300, NN = 300, DD = 256;
constexpr int WHX = 9216, BQ = 2400, SIMW = 600;
constexpr int QP = 320;
constexpr int CP = 304;   // padded C rows (19 MFMA tiles; rows 300..303 zero)
constexpr int KP = 96;
constexpr int NP = 416;
constexpr int CELLCAP = 300;

// ---------------- workspace layout (float units) ----------------
constexpr size_t F_SIMS   = 0;
constexpr size_t F_GTSIM  = F_SIMS   + (size_t)BQ*SIMW;
constexpr size_t F_MM     = F_GTSIM  + (size_t)NN*CC;
constexpr size_t F_SCORE  = F_MM     + (size_t)NN*NN;
constexpr size_t F_BBOX   = F_SCORE  + BQ;
constexpr size_t F_TB     = F_BBOX   + (size_t)BQ*4;
constexpr size_t F_SB     = F_TB     + (size_t)NN*4;
constexpr size_t F_SAREA  = F_SB     + (size_t)BQ*4;
constexpr size_t F_KB     = F_SAREA  + BQ;
constexpr size_t F_ROWSUM = F_KB     + (size_t)BQ*4;
constexpr size_t F_OE     = F_ROWSUM + NN;                     // ---- zeroed zone
constexpr size_t F_GSEL   = F_OE     + (size_t)NN*DD;
constexpr size_t F_MSUM   = F_GSEL   + (size_t)NN*4;
constexpr size_t F_STGT   = F_MSUM   + NN;
constexpr size_t F_SC     = F_STGT   + 8;
constexpr size_t F_CNT    = F_SC     + 16;
constexpr size_t F_ACCEND = F_CNT    + BQ;                     // ---- end zeroed zone
constexpr size_t F_ORDER  = F_ACCEND;
constexpr size_t F_NMSIDX = F_ORDER  + BQ;
constexpr size_t F_SEL2   = F_NMSIDX + BQ;
constexpr size_t F_BSTART = F_SEL2   + NN;
constexpr size_t F_KINT   = F_BSTART + 16;
constexpr size_t F_CLS    = F_KINT   + 4;
constexpr size_t F_KEEPF  = F_CLS    + BQ;
constexpr size_t F_LIST   = F_KEEPF  + BQ;
constexpr size_t F_S2T    = F_LIST   + (size_t)BQ*CELLCAP;     // f32 [300][2400]
constexpr size_t F_SIMTB  = ((F_S2T + (size_t)NN*BQ + 7) & ~(size_t)7);  // u16[8][304][320]
constexpr size_t F_OMT    = F_SIMTB + (size_t)BB*CP*QP/2;
constexpr size_t F_TMT    = F_OMT   + (size_t)WHX*QP/2;
constexpr size_t F_GTP    = F_TMT   + (size_t)WHX*NP/2;        // u16[8][304][96]
constexpr size_t F_TOTAL  = F_GTP   + (size_t)BB*CP*KP/2;

// ---------------- JAX threefry2x32 (partitionable scheme) ----------------
DEVFN uint32_t rotl32(uint32_t v, int r){ return (v << r) | (v >> (32 - r)); }

DEVFN void tf2x32(uint32_t k0, uint32_t k1, uint32_t x0, uint32_t x1,
                  uint32_t& o0, uint32_t& o1){
  uint32_t ks2 = k0 ^ k1 ^ 0x1BD11BDAu;
  x0 += k0; x1 += k1;
#define TFR(r) x0 += x1; x1 = rotl32(x1, r); x1 ^= x0;
  TFR(13) TFR(15) TFR(26) TFR(6)   x0 += k1;  x1 += ks2 + 1u;
  TFR(17) TFR(29) TFR(16) TFR(24)  x0 += ks2; x1 += k0  + 2u;
  TFR(13) TFR(15) TFR(26) TFR(6)   x0 += k0;  x1 += k1  + 3u;
  TFR(17) TFR(29) TFR(16) TFR(24)  x0 += k1;  x1 += ks2 + 4u;
  TFR(13) TFR(15) TFR(26) TFR(6)   x0 += ks2; x1 += k0  + 5u;
#undef TFR
  o0 = x0; o1 = x1;
}

DEVFN void subkey(int i, uint32_t& k0, uint32_t& k1){
  tf2x32(0u, 42u, 0u, (uint32_t)i, k0, k1);
}

DEVFN float gumbel32(uint32_t k0, uint32_t k1, uint32_t idx){
  uint32_t h, l; tf2x32(k0, k1, 0u, idx, h, l);
  uint32_t bits = h ^ l;
  float f = __uint_as_float((bits >> 9) | 0x3F800000u) - 1.0f;
  const float tiny = 1.17549435e-38f;
  float u = fmaxf(tiny, f + tiny);
  return -logf(-logf(u));
}

DEVFN float iou_xyxy(float ax1,float ay1,float ax2,float ay2,
                     float bx1,float by1,float bx2,float by2){
  float aa = (ax2-ax1)*(ay2-ay1);
  float ab = (bx2-bx1)*(by2-by1);
  float lx = fmaxf(ax1,bx1), ly = fmaxf(ay1,by1);
  float rx = fminf(ax2,bx2), ry = fminf(ay2,by2);
  float iw = fmaxf(rx-lx,0.f), ih = fmaxf(ry-ly,0.f);
  float in_ = iw*ih;
  return in_/(aa+ab-in_);
}

DEVFN u16 f2bf(float x){
  uint32_t u = __float_as_uint(x);
  uint32_t r = u + 0x7FFFu + ((u >> 16) & 1u);
  return (u16)(r >> 16);
}

DEVFN void gload_lds16(const u16* g, u16* l){
  __builtin_amdgcn_global_load_lds(
      (const __attribute__((address_space(1))) unsigned int*)g,
      (__attribute__((address_space(3))) unsigned int*)l,
      16, 0, 0);
}

// ---------------- K1: tiled f32 GEMM 64x64 + s2T side-write ----------------
__global__ __launch_bounds__(256) void k_gemm_t(
    const float* __restrict__ pl, const float* __restrict__ ce,
    const float* __restrict__ te, float* __restrict__ sims,
    float* __restrict__ gtsim, float* __restrict__ s2t){
  __shared__ float As[16][64];
  __shared__ float Bs[16][64];
  const int row0 = blockIdx.x * 64, col0 = blockIdx.y * 64;
  const int tid = threadIdx.x;
  const int lrow = tid >> 2, lk0 = (tid & 3) * 4;
  const int tr = tid >> 4, tc = tid & 15;

  float acc[4][4];
  #pragma unroll
  for (int i = 0; i < 4; i++)
    #pragma unroll
    for (int j = 0; j < 4; j++) acc[i][j] = 0.f;

  const float4 z4 = {0.f,0.f,0.f,0.f};
  const int grow = row0 + lrow;
  const int gcol = col0 + lrow;
  const float* arow = nullptr;
  if (grow < 2400) arow = pl + (size_t)grow * DD;
  else if (grow < 2700) arow = te + (size_t)(grow - 2400) * DD;
  const float* brow = nullptr;
  if (gcol < 300) brow = ce + (size_t)gcol * DD;
  else if (gcol < 600) brow = te + (size_t)(gcol - 300) * DD;

  float4 av = arow ? *(const float4*)(arow + lk0) : z4;
  float4 bv = brow ? *(const float4*)(brow + lk0) : z4;

  for (int step = 0; step < 16; step++){
    __syncthreads();
    #pragma unroll
    for (int j = 0; j < 4; j++){
      As[lk0 + j][lrow] = ((const float*)&av)[j];
      Bs[lk0 + j][lrow] = ((const float*)&bv)[j];
    }
    __syncthreads();
    if (step + 1 < 16){
      const int k0 = (step + 1) * 16;
      av = arow ? *(const float4*)(arow + k0 + lk0) : z4;
      bv = brow ? *(const float4*)(brow + k0 + lk0) : z4;
    }
    #pragma unroll
    for (int kk = 0; kk < 16; kk++){
      float4 a4 = *(const float4*)&As[kk][tr*4];
      float4 b4 = *(const float4*)&Bs[kk][tc*4];
      float a[4] = {a4.x,a4.y,a4.z,a4.w};
      float b[4] = {b4.x,b4.y,b4.z,b4.w};
      #pragma unroll
      for (int i = 0; i < 4; i++)
        #pragma unroll
        for (int j = 0; j < 4; j++)
          acc[i][j] = fmaf(a[i], b[j], acc[i][j]);
    }
  }

  #pragma unroll
  for (int i = 0; i < 4; i++){
    const int r = row0 + tr*4 + i;
    const int c0 = col0 + tc*4;
    if (r < 2400){
      if (c0 < 600){
        float4 o0 = {acc[i][0],acc[i][1],acc[i][2],acc[i][3]};
        *(float4*)(sims + (size_t)r*SIMW + c0) = o0;
        if (c0 >= 300){
          #pragma unroll
          for (int j = 0; j < 4; j++)
            s2t[(size_t)(c0 + j - 300)*BQ + r] = acc[i][j];
        }
      }
    } else if (r < 2700){
      const int n = r - 2400;
      #pragma unroll
      for (int j = 0; j < 4; j++){
        int c = c0 + j;
        if (c < 300) gtsim[(size_t)n*CC + c] = acc[i][j];
      }
    }
  }
}

// ---------------- K2: per-bq scores/argmax(g0)/boxes/cls; tb rows; gtsim rowsums ----------------
__global__ __launch_bounds__(256) void k_post(
    const float* __restrict__ sims, const float* __restrict__ pb,
    const float* __restrict__ tbb, const int* __restrict__ tids,
    const int* __restrict__ bidx, const float* __restrict__ gtsim,
    float* __restrict__ score, float* __restrict__ bbox,
    float* __restrict__ tb, float* __restrict__ rowsum,
    int* __restrict__ clsout){
  int bq = blockIdx.x, tid = threadIdx.x;
  __shared__ float sv[256];
  __shared__ int   si[256];
  const int i2 = tid + 256;
  float v1 = (tid < CC) ? sims[(size_t)bq*SIMW + tid] : -INFINITY;
  float v2 = (i2  < CC) ? sims[(size_t)bq*SIMW + i2]  : -INFINITY;
  sv[tid] = fmaxf(v1, v2); __syncthreads();
  for (int s = 128; s > 0; s >>= 1){ if (tid < s) sv[tid] = fmaxf(sv[tid], sv[tid+s]); __syncthreads(); }
  if (tid == 0) score[bq] = sv[0];
  __syncthreads();
  uint32_t gk0, gk1; subkey(0, gk0, gk1);
  float y1 = (tid < CC) ? v1 + gumbel32(gk0, gk1, (uint32_t)(bq*CC + tid)) : -INFINITY;
  float y2 = (i2  < CC) ? v2 + gumbel32(gk0, gk1, (uint32_t)(bq*CC + i2))  : -INFINITY;
  float ym; int yi;
  if (y2 > y1){ ym = y2; yi = i2; } else { ym = y1; yi = tid; }
  sv[tid] = ym; si[tid] = yi; __syncthreads();
  for (int s = 128; s > 0; s >>= 1){
    if (tid < s){
      float ov = sv[tid+s]; int oi = si[tid+s];
      if (ov > sv[tid] || (ov == sv[tid] && oi < si[tid])){ sv[tid] = ov; si[tid] = oi; }
    }
    __syncthreads();
  }
  if (tid == 0){
    int cls = si[0];
    clsout[bq] = cls;
    float ox = 224.0f * (float)cls;
    float oy = 224.0f * (float)(bq / QQ);
    float cx = pb[bq*4+0], cy = pb[bq*4+1], ww = pb[bq*4+2], hh = pb[bq*4+3];
    bbox[bq*4+0] = cx - 0.5f*ww + ox;
    bbox[bq*4+1] = cy - 0.5f*hh + oy;
    bbox[bq*4+2] = cx + 0.5f*ww + ox;
    bbox[bq*4+3] = cy + 0.5f*hh + oy;
  }
  if (bq < NN){
    __syncthreads();
    float r1 = (tid < CC) ? gtsim[(size_t)bq*CC + tid] : 0.f;
    float r2 = (i2  < CC) ? gtsim[(size_t)bq*CC + i2]  : 0.f;
    sv[tid] = r1 + r2; __syncthreads();
    for (int s = 128; s > 0; s >>= 1){ if (tid < s) sv[tid] += sv[tid+s]; __syncthreads(); }
    if (tid == 0) rowsum[bq] = sv[0];
    if (tid == 1){
      float gx = 224.0f * (float)tids[bq], gy = 224.0f * (float)bidx[bq];
      float cx = tbb[bq*4+0], cy = tbb[bq*4+1], ww = tbb[bq*4+2], hh = tbb[bq*4+3];
      tb[bq*4+0] = cx - 0.5f*ww + gx;
      tb[bq*4+1] = cy - 0.5f*hh + gy;
      tb[bq*4+2] = cx + 0.5f*ww + gx;
      tb[bq*4+3] = cy + 0.5f*hh + gy;
    }
  }
}

// ---------------- K3: fused rank + gather + bucket ----------------
__global__ __launch_bounds__(256) void k_rankgather(
    const float* __restrict__ score, const float* __restrict__ bbox,
    const int* __restrict__ cls, const int* __restrict__ bidx,
    int* __restrict__ order, float* __restrict__ sb,
    int* __restrict__ bstart, int* __restrict__ cnt,
    int* __restrict__ list){
  const int t = blockIdx.x;
  const int tid = threadIdx.x;
  const float st = score[t];
  int c = 0;
  for (int j = tid; j < BQ; j += 256){
    float sj = score[j];
    c += (sj > st) || (sj == st && j < t);
  }
  __shared__ int red[256];
  red[tid] = c; __syncthreads();
  for (int s = 128; s > 0; s >>= 1){
    if (tid < s) red[tid] += red[tid+s];
    __syncthreads();
  }
  if (tid == 0){
    int r = red[0];
    order[r] = t;
    float x1 = bbox[t*4+0], y1 = bbox[t*4+1], x2 = bbox[t*4+2], y2 = bbox[t*4+3];
    sb[r*4+0] = x1; sb[r*4+1] = y1; sb[r*4+2] = x2; sb[r*4+3] = y2;
    int key = (t / QQ) * CC + cls[t];
    int slot = atomicAdd(&cnt[key], 1);
    list[(size_t)key*CELLCAP + slot] = r;
  }
  if (t == 0 && tid >= 32 && tid < 41){
    int b = tid - 32, cb = 0;
    for (int n = 0; n < NN; n++) cb += (bidx[n] < b);
    bstart[b] = cb;
  }
}

// ---------------- K6': per-cell greedy NMS ----------------
__global__ __launch_bounds__(256) void k_cellnms(
    const float* __restrict__ sb, const int* __restrict__ cnt,
    const int* __restrict__ list, int* __restrict__ keepf){
  int key = blockIdx.x*256 + threadIdx.x;
  if (key >= BB*CC) return;
  int m = cnt[key];
  if (m <= 0) return;
  const int* lst = list + (size_t)key*CELLCAP;
  unsigned long long keptmask = 0ull;
  int prevp = -1;
  for (int a = 0; a < m; a++){
    int pa = 0x7fffffff;
    for (int j = 0; j < m; j++){
      int pj = lst[j];
      if (pj > prevp && pj < pa) pa = pj;
    }
    prevp = pa;
    float4 A = ((const float4*)sb)[pa];
    float areaA = (A.z-A.x)*(A.w-A.y);
    bool kept = true;
    int pbprev = -1;
    for (int b2 = 0; b2 < a; b2++){
      int pb = 0x7fffffff;
      for (int j = 0; j < m; j++){
        int pj = lst[j];
        if (pj > pbprev && pj < pb) pb = pj;
      }
      pbprev = pb;
      bool keptb = (m <= 64) ? (((keptmask >> b2) & 1ull) != 0ull) : (keepf[pb] != 0);
      if (!keptb) continue;
      float4 B = ((const float4*)sb)[pb];
      float areaB = (B.z-B.x)*(B.w-B.y);
      float lx = fmaxf(A.x,B.x), ly = fmaxf(A.y,B.y);
      float rx = fminf(A.z,B.z), ry = fminf(A.w,B.w);
      float iw = fmaxf(rx-lx,0.f), ih = fmaxf(ry-ly,0.f);
      float inter = iw*ih;
      if (inter/(areaA + areaB - inter) > 0.5f){ kept = false; break; }
    }
    if (m <= 64 && kept) keptmask |= (1ull << a);
    keepf[pa] = kept ? 1 : 0;
  }
}

// ---------------- K7: compact ----------------
__global__ __launch_bounds__(256) void k_compact(
    const int* __restrict__ keepflag, const int* __restrict__ order,
    const float* __restrict__ sb, int* __restrict__ nmsidx,
    float* __restrict__ kb, int* __restrict__ kint){
  __shared__ int csum[256];
  int tid = threadIdx.x;
  int p0 = tid*10;
  int keepf[10];
  int cnt = 0;
  #pragma unroll
  for (int d = 0; d < 10; d++){
    int p = p0 + d;
    int k = 0;
    if (p < BQ) k = keepflag[p];
    keepf[d] = k; cnt += k;
  }
  csum[tid] = cnt; __syncthreads();
  for (int s = 1; s < 256; s <<= 1){
    int add = (tid >= s) ? csum[tid - s] : 0;
    __syncthreads();
    csum[tid] += add;
    __syncthreads();
  }
  int pos = csum[tid] - cnt;
  #pragma unroll
  for (int d = 0; d < 10; d++){
    if (keepf[d]){
      int p = p0 + d;
      nmsidx[pos] = order[p];
      ((float4*)kb)[pos] = ((const float4*)sb)[p];
      pos++;
    }
  }
  if (tid == 255) kint[0] = csum[255];
}

// ---------------- K8: per-kept-box scatter ----------------
__global__ __launch_bounds__(512) void k_gtsel(
    const float* __restrict__ kb, const float* __restrict__ tb,
    const int* __restrict__ nmsidx, const float* __restrict__ pl,
    const int* __restrict__ kint, float* __restrict__ gsel,
    float* __restrict__ oe){
  int k = blockIdx.x;
  if (k >= kint[0]) return;
  int tid = threadIdx.x;
  __shared__ float sv[512];
  __shared__ int   si[512];
  float4 a = ((const float4*)kb)[k];
  float iou = -INFINITY;
  if (tid < NN){
    float4 t = ((const float4*)tb)[tid];
    iou = iou_xyxy(a.x,a.y,a.z,a.w, t.x,t.y,t.z,t.w);
    if (iou != iou) iou = 0.f;
  }
  sv[tid] = iou; __syncthreads();
  for (int s = 256; s > 0; s >>= 1){ if (tid < s) sv[tid] = fmaxf(sv[tid], sv[tid+s]); __syncthreads(); }
  float m = sv[0]; __syncthreads();
  float e = (tid < NN) ? expf(iou - m) : 0.f;
  sv[tid] = e; __syncthreads();
  for (int s = 256; s > 0; s >>= 1){ if (tid < s) sv[tid] += sv[tid+s]; __syncthreads(); }
  float S = sv[0]; __syncthreads();
  uint32_t gk0, gk1; subkey(1, gk0, gk1);
  float y = (tid < NN) ? (e / S + gumbel32(gk0, gk1, (uint32_t)(k*NN + tid))) : -INFINITY;
  sv[tid] = y; si[tid] = tid; __syncthreads();
  for (int s = 256; s > 0; s >>= 1){
    if (tid < s){
      float ov = sv[tid+s]; int oi = si[tid+s];
      if (ov > sv[tid] || (ov == sv[tid] && oi < si[tid])){ sv[tid] = ov; si[tid] = oi; }
    }
    __syncthreads();
  }
  int sel = si[0];
  if (tid < 4) atomicAdd(&gsel[sel*4 + tid], ((const float*)&a)[tid]);
  if (tid < DD) atomicAdd(&oe[(size_t)sel*DD + tid], pl[(size_t)nmsidx[k]*DD + tid]);
}

// ---------------- K10: tiled M = te @ oe^T (32x32 tiles) ----------------
__global__ __launch_bounds__(256) void k_m_t(
    const float* __restrict__ te, const float* __restrict__ oe,
    float* __restrict__ M){
  __shared__ float As[16][32];
  __shared__ float Bs[16][32];
  const int row0 = blockIdx.x * 32, col0 = blockIdx.y * 32;
  const int tid = threadIdx.x;
  const int lr = tid >> 3, lk0 = (tid & 7) * 2;
  const int tr = tid >> 4, tc = tid & 15;
  float acc[2][2] = {{0.f,0.f},{0.f,0.f}};
  const float* arow = (row0 + lr < NN) ? te + (size_t)(row0 + lr)*DD : nullptr;
  const float* brow = (col0 + lr < NN) ? oe + (size_t)(col0 + lr)*DD : nullptr;
  for (int step = 0; step < 16; step++){
    const int k0 = step*16;
    float2 a2 = arow ? *(const float2*)(arow + k0 + lk0) : float2{0.f,0.f};
    float2 b2 = brow ? *(const float2*)(brow + k0 + lk0) : float2{0.f,0.f};
    __syncthreads();
    As[lk0][lr] = a2.x; As[lk0+1][lr] = a2.y;
    Bs[lk0][lr] = b2.x; Bs[lk0+1][lr] = b2.y;
    __syncthreads();
    #pragma unroll
    for (int kk = 0; kk < 16; kk++){
      float a0 = As[kk][tr*2], a1 = As[kk][tr*2+1];
      float b0 = Bs[kk][tc*2], b1 = Bs[kk][tc*2+1];
      acc[0][0] = fmaf(a0,b0,acc[0][0]);
      acc[0][1] = fmaf(a0,b1,acc[0][1]);
      acc[1][0] = fmaf(a1,b0,acc[1][0]);
      acc[1][1] = fmaf(a1,b1,acc[1][1]);
    }
  }
  #pragma unroll
  for (int i = 0; i < 2; i++){
    int r = row0 + tr*2 + i;
    if (r >= NN) continue;
    #pragma unroll
    for (int j = 0; j < 2; j++){
      int c = col0 + tc*2 + j;
      if (c < NN) M[(size_t)r*NN + c] = acc[i][j];
    }
  }
}

// ---------------- K11: both cross-entropies ----------------
__global__ __launch_bounds__(64) void k_ce(
    const float* __restrict__ M, float* __restrict__ sc){
  int i = blockIdx.x, lane = threadIdx.x;
  float m = -INFINITY;
  for (int j = lane; j < NN; j += 64) m = fmaxf(m, M[(size_t)i*NN + j]);
  for (int o = 32; o > 0; o >>= 1) m = fmaxf(m, __shfl_xor(m, o));
  float s = 0.f;
  for (int j = lane; j < NN; j += 64) s += expf(M[(size_t)i*NN + j] - m);
  for (int o = 32; o > 0; o >>= 1) s += __shfl_xor(s, o);
  float lr = m + logf(s);
  float m2 = -INFINITY;
  for (int j = lane; j < NN; j += 64) m2 = fmaxf(m2, M[(size_t)j*NN + i]);
  for (int o = 32; o > 0; o >>= 1) m2 = fmaxf(m2, __shfl_xor(m2, o));
  float s2 = 0.f;
  for (int j = lane; j < NN; j += 64) s2 += expf(M[(size_t)j*NN + i] - m2);
  for (int o = 32; o > 0; o >>= 1) s2 += __shfl_xor(s2, o);
  float lc = m2 + logf(s2);
  if (lane == 0){
    float d = M[(size_t)i*NN + i];
    atomicAdd(&sc[0], lr - d);
    atomicAdd(&sc[1], lc - d);
  }
}

// ---------------- K12: sel2 (coalesced via s2T) ----------------
__global__ __launch_bounds__(256) void k_sel2(
    const float* __restrict__ s2t, int* __restrict__ sel2){
  int n = blockIdx.x, tid = threadIdx.x;
  uint32_t gk0, gk1; subkey(2, gk0, gk1);
  float best = -INFINITY; int bi = 0x7fffffff;
  for (int r = tid; r < BQ; r += 256){
    float v = s2t[(size_t)n*BQ + r] + gumbel32(gk0, gk1, (uint32_t)(r*NN + n));
    if (v > best){ best = v; bi = r; }
  }
  __shared__ float sv[256];
  __shared__ int   si[256];
  sv[tid] = best; si[tid] = bi; __syncthreads();
  for (int s = 128; s > 0; s >>= 1){
    if (tid < s){
      float ov = sv[tid+s]; int oi = si[tid+s];
      if (ov > sv[tid] || (ov == sv[tid] && oi < si[tid])){ sv[tid] = ov; si[tid] = oi; }
    }
    __syncthreads();
  }
  if (tid == 0) sel2[n] = si[0];
}

// ---------------- K_PACK: fused transposes + om-loss (4 ranges; OM fused into OMT) ----------------
constexpr int PB_SIMT = 400;                // (10 q) x (5 c) x 8 b
constexpr int PB_OMT  = 1440;               // (10 q) x 144 wh  (also computes om-loss + masksum)
constexpr int PB_TMT  = 1872;               // (13 n) x 144 wh
constexpr int PB_GTP  = 114;                // 8*304*12 / 256
__global__ __launch_bounds__(256) void k_pack(
    const float* __restrict__ sims, const float* __restrict__ pm,
    const float* __restrict__ tm, const float* __restrict__ gtsim,
    const int* __restrict__ sel2, const int* __restrict__ bstart,
    u16* __restrict__ simTb, u16* __restrict__ omT,
    u16* __restrict__ tmT, u16* __restrict__ gtp,
    float* __restrict__ msum, float* __restrict__ sc){
  __shared__ float ld[32][65];
  __shared__ float sm_ts[32];
  __shared__ float sm_d2;
  const int blk = blockIdx.x;
  const int tid = threadIdx.x;

  if (blk < PB_SIMT){
    int bx = blk % 10, by = (blk / 10) % 5, b = blk / 50;
    int q0 = bx*32, c0 = by*64;
    for (int i = tid; i < 32*64; i += 256){
      int qi = i >> 6, ci = i & 63;
      int q = q0 + qi, c = c0 + ci;
      ld[qi][ci] = (q < QQ && c < CC) ? sims[((size_t)b*QQ + q)*SIMW + c] : 0.f;
    }
    __syncthreads();
    int cloc = tid >> 2, j0 = (tid & 3)*8;
    int c = c0 + cloc;
    if (c < CP){
      u16 tmp[8];
      #pragma unroll
      for (int j = 0; j < 8; j++) tmp[j] = f2bf(ld[j0+j][cloc]);
      *(uint4*)(simTb + ((size_t)b*CP + c)*QP + q0 + j0) = *(const uint4*)tmp;
    }
  } else if (blk < PB_SIMT + PB_OMT){
    // OMT transpose + fused overall-mask-loss / masksum (raw pm, scale at write)
    int r = blk - PB_SIMT;
    int q0 = (r % 10)*32, wh0 = (r / 10)*64;
    if (tid < 32) sm_ts[tid] = 0.f;
    if (tid == 32) sm_d2 = 0.f;
    __syncthreads();
    float d2loc = 0.f;
    for (int i = tid; i < 32*64; i += 256){
      int qi = i >> 6, wi = i & 63;
      int q = q0 + qi;
      float pv = 0.f;
      if (q < QQ){
        pv = pm[(size_t)sel2[q]*WHX + wh0 + wi];
        float tv = tm[(size_t)q*WHX + wh0 + wi];
        float d = pv - tv;
        d2loc += d*d;
        atomicAdd(&sm_ts[qi], tv);
      }
      ld[qi][wi] = pv;
    }
    atomicAdd(&sm_d2, d2loc);
    __syncthreads();
    int wloc = tid >> 2, j0 = (tid & 3)*8;
    u16 tmp[8];
    #pragma unroll
    for (int j = 0; j < 8; j++) tmp[j] = f2bf(ld[j0+j][wloc] * (1.0f/96.0f));
    *(uint4*)(omT + (size_t)(wh0+wloc)*QP + q0 + j0) = *(const uint4*)tmp;
    if (tid < 32 && q0 + tid < NN) atomicAdd(&msum[q0 + tid], sm_ts[tid]);
    if (tid == 32) atomicAdd(&sc[2], sm_d2);
  } else if (blk < PB_SIMT + PB_OMT + PB_TMT){
    int r = blk - PB_SIMT - PB_OMT;
    int n0 = (r % 13)*32, wh0 = (r / 13)*64;
    for (int i = tid; i < 32*64; i += 256){
      int ni = i >> 6, wi = i & 63;
      int n = n0 + ni;
      ld[ni][wi] = (n < NN) ? tm[(size_t)n*WHX + wh0 + wi] : 0.f;
    }
    __syncthreads();
    int wloc = tid >> 2, j0 = (tid & 3)*8;
    u16 tmp[8];
    #pragma unroll
    for (int j = 0; j < 8; j++) tmp[j] = f2bf(ld[j0+j][wloc]);
    *(uint4*)(tmT + (size_t)(wh0+wloc)*NP + n0 + j0) = *(const uint4*)tmp;
  } else {
    int g = (blk - PB_SIMT - PB_OMT - PB_TMT)*256 + tid;
    int b = g / (CP*(KP/8));
    int rem = g - b*(CP*(KP/8));
    int c = rem / (KP/8);
    int kg = rem % (KP/8);
    int n0 = bstart[b], n1 = bstart[b+1];
    int kst = n0 & ~7;
    u16 tmp[8];
    #pragma unroll
    for (int j = 0; j < 8; j++){
      int n = kst + kg*8 + j;
      float v = (n >= n0 && n < n1 && c < CC) ? gtsim[(size_t)n*CC + c] : 0.f;
      tmp[j] = f2bf(v);
    }
    *(uint4*)(gtp + ((size_t)b*CP + c)*KP + kg*8) = *(const uint4*)tmp;
  }
}

// ---------------- K15: MFMA z-GEMM + column softmax + dice (round-14 form) ----------------
constexpr int ALDS = 32;
__global__ __launch_bounds__(256) void k_zsoft(
    const u16* __restrict__ simTb, const u16* __restrict__ omT,
    const u16* __restrict__ gtp, const u16* __restrict__ tmT,
    const int* __restrict__ bstart, float* __restrict__ sc){
  const int bid = blockIdx.x;
  const int xcd = bid & 7;
  const int r9  = bid >> 3;
  const int tile = xcd * 18 + (r9 % 18);
  const int b    = r9 / 18;
  const int tid = threadIdx.x;
  const int w = tid >> 6, l = tid & 63;
  const int lrow = l & 15, lgrp = l >> 4;
  const int col = tile*64 + w*16 + lrow;

  __shared__ u16 As[2][CP*ALDS];
  __shared__ float red[256];

  const u16* Ab = simTb + (size_t)b*CP*QP;
  int srcoff[5];
  #pragma unroll
  for (int i = 0; i < 5; i++){
    int p = (w*5 + i)*64 + l;
    int row = p >> 2, cs = p & 3;
    int g = cs ^ ((row >> 1) & 3);
    srcoff[i] = row*QP + g*8;
  }
  const int nIss = (w == 3) ? 4 : 5;
  const int roff = (lgrp ^ ((lrow >> 1) & 3)) << 3;
  const u16* pB = omT + (size_t)col*QP + lgrp*8;

  #pragma unroll
  for (int i = 0; i < 5; i++){
    if (i < nIss) gload_lds16(Ab + srcoff[i], &As[0][(w*5+i)*512]);
  }
  bf16x8 bcur = *(const bf16x8*)(pB);

  f32x4 acc[19];
  #pragma unroll
  for (int t = 0; t < 19; t++) acc[t] = (f32x4){0.f,0.f,0.f,0.f};
  __syncthreads();

  for (int ks = 0; ks < 10; ks++){
    const int cur = ks & 1;
    bf16x8 bnext;
    if (ks + 1 < 10){
      const int ko = (ks + 1) * 32;
      #pragma unroll
      for (int i = 0; i < 5; i++){
        if (i < nIss) gload_lds16(Ab + srcoff[i] + ko, &As[cur ^ 1][(w*5+i)*512]);
      }
      bnext = *(const bf16x8*)(pB + ko);
    }
    __builtin_amdgcn_s_setprio(1);
    #pragma unroll
    for (int t = 0; t < 19; t++){
      bf16x8 af = *(const bf16x8*)&As[cur][t*16*ALDS + lrow*ALDS + roff];
      acc[t] = __builtin_amdgcn_mfma_f32_16x16x32_bf16(af, bcur, acc[t], 0, 0, 0);
    }
    __builtin_amdgcn_s_setprio(0);
    bcur = bnext;
    __syncthreads();
  }

  float lmax = -INFINITY;
  #pragma unroll
  for (int t = 0; t < 19; t++){
    if (t == 18 && lgrp == 3) continue;
    lmax = fmaxf(lmax, fmaxf(fmaxf(acc[t][0], acc[t][1]), fmaxf(acc[t][2], acc[t][3])));
  }
  lmax = fmaxf(lmax, __shfl_xor(lmax, 16));
  lmax = fmaxf(lmax, __shfl_xor(lmax, 32));
  float ls = 0.f;
  #pragma unroll
  for (int t = 0; t < 19; t++){
    if (t == 18 && lgrp == 3){
      acc[t] = (f32x4){0.f,0.f,0.f,0.f};
      continue;
    }
    float p0 = __expf(acc[t][0] - lmax);
    float p1 = __expf(acc[t][1] - lmax);
    float p2 = __expf(acc[t][2] - lmax);
    float p3 = __expf(acc[t][3] - lmax);
    acc[t][0] = p0; acc[t][1] = p1; acc[t][2] = p2; acc[t][3] = p3;
    ls += p0 + p1 + p2 + p3;
  }
  float S = ls;
  S += __shfl_xor(S, 16);
  S += __shfl_xor(S, 32);
  float inv = 1.f / S;

  const int n0 = bstart[b];
  const int kst = n0 & ~7;
  const u16* tB = tmT + (size_t)col*NP + kst + lgrp*8;
  bf16x8 b2a = *(const bf16x8*)(tB);
  bf16x8 b2b = *(const bf16x8*)(tB + 32);
  bf16x8 b2c = *(const bf16x8*)(tB + 64);
  const u16* A2 = gtp + (size_t)b*CP*KP + (size_t)lrow*KP + lgrp*8;
  float dl = 0.f;
  #pragma unroll
  for (int t = 0; t < 19; t++){
    const u16* ar = A2 + (size_t)t*16*KP;
    f32x4 rr = (f32x4){0.f,0.f,0.f,0.f};
    rr = __builtin_amdgcn_mfma_f32_16x16x32_bf16(*(const bf16x8*)(ar),      b2a, rr, 0, 0, 0);
    rr = __builtin_amdgcn_mfma_f32_16x16x32_bf16(*(const bf16x8*)(ar + 32), b2b, rr, 0, 0, 0);
    rr = __builtin_amdgcn_mfma_f32_16x16x32_bf16(*(const bf16x8*)(ar + 64), b2c, rr, 0, 0, 0);
    dl += acc[t][0]*rr[0] + acc[t][1]*rr[1] + acc[t][2]*rr[2] + acc[t][3]*rr[3];
  }
  dl *= inv;

  red[tid] = dl; __syncthreads();
  for (int s = 128; s > 0; s >>= 1){
    if (tid < s) red[tid] += red[tid+s];
    __syncthreads();
  }
  if (tid == 0) atomicAdd(&sc[5], red[0]);
}

// ---------------- K16: fused gtiou + sumtgt + finalize ----------------
__global__ __launch_bounds__(512) void k_final3(
    const float* __restrict__ gsel, const float* __restrict__ tb,
    const int* __restrict__ bidx, const float* __restrict__ rowsum,
    const float* __restrict__ msum, const float* __restrict__ sc,
    const int* __restrict__ kint, float* __restrict__ out){
  int tid = threadIdx.x;
  __shared__ float s1[512], s2[512];
  __shared__ float stgt[8];
  if (tid < 8) stgt[tid] = 0.f;
  __syncthreads();
  float a1 = 0.f, a2 = 0.f;
  if (tid < NN){
    float4 g = ((const float4*)gsel)[tid];
    float4 t = ((const float4*)tb)[tid];
    float iou = iou_xyxy(g.x,g.y,g.z,g.w, t.x,t.y,t.z,t.w);
    a1 = 1.f - iou;
    a2 = fabsf(g.x-t.x) + fabsf(g.y-t.y) + fabsf(g.z-t.z) + fabsf(g.w-t.w);
    atomicAdd(&stgt[bidx[tid]], rowsum[tid] * msum[tid]);
  }
  s1[tid] = a1; s2[tid] = a2; __syncthreads();
  for (int s = 256; s > 0; s >>= 1){
    if (tid < s){ s1[tid] += s1[tid+s]; s2[tid] += s2[tid+s]; }
    __syncthreads();
  }
  if (tid == 0){
    float K = (float)kint[0];
    float cls = sc[0]/300.f + sc[1]/300.f;
    float stot = sc[5];
    float dice = 0.f;
    for (int b = 0; b < 8; b++) dice += stot / (9216.0f + stgt[b] + 1e-6f);
    dice *= (1.0f/8.0f);
    out[0] = cls;
    out[1] = dice;
    out[2] = (sc[2] / 2764800.0f) / K;
    out[3] = s1[0] / K;
    out[4] = s2[0] / K;
  }
}

// ---------------- launch ----------------
extern "C" void kernel_launch(void* const* d_in, const int* in_sizes, int n_in,
                              void* d_out, int out_size, void* d_ws, size_t ws_size,
                              hipStream_t stream) {
  const float* ce  = (const float*)d_in[0];
  const float* pl  = (const float*)d_in[1];
  const float* pb  = (const float*)d_in[2];
  const float* pm  = (const float*)d_in[3];
  const float* tm  = (const float*)d_in[4];
  const float* te  = (const float*)d_in[5];
  const float* tbb = (const float*)d_in[6];
  const int*  tids = (const int*)d_in[8];
  const int*  bidx = (const int*)d_in[9];
  float* out = (float*)d_out;
  float* w = (float*)d_ws;

  if (ws_size < F_TOTAL * sizeof(float)) return;

  float* SIMS   = w + F_SIMS;
  float* GTSIM  = w + F_GTSIM;
  float* MM     = w + F_MM;
  float* SCORE  = w + F_SCORE;
  float* BBOX   = w + F_BBOX;
  float* TBOX   = w + F_TB;
  float* SB     = w + F_SB;
  float* KB     = w + F_KB;
  float* ROWSUM = w + F_ROWSUM;
  float* OE     = w + F_OE;
  float* GSEL   = w + F_GSEL;
  float* MSUM   = w + F_MSUM;
  float* SC     = w + F_SC;
  float* S2T    = w + F_S2T;
  int*   CNT    = (int*)(w + F_CNT);
  int*   ORDER  = (int*)(w + F_ORDER);
  int*   NMSIDX = (int*)(w + F_NMSIDX);
  int*   SEL2   = (int*)(w + F_SEL2);
  int*   BSTART = (int*)(w + F_BSTART);
  int*   KINT   = (int*)(w + F_KINT);
  int*   CLS    = (int*)(w + F_CLS);
  int*   KEEPF  = (int*)(w + F_KEEPF);
  int*   LIST   = (int*)(w + F_LIST);
  u16* SIMTB = (u16*)(w + F_SIMTB);
  u16* OMT   = (u16*)(w + F_OMT);
  u16* TMT   = (u16*)(w + F_TMT);
  u16* GTP   = (u16*)(w + F_GTP);

  hipMemsetAsync(w + F_OE, 0, (F_ACCEND - F_OE) * sizeof(float), stream);

  k_gemm_t<<<dim3(43, 10), 256, 0, stream>>>(pl, ce, te, SIMS, GTSIM, S2T);
  k_post<<<BQ, 256, 0, stream>>>(SIMS, pb, tbb, tids, bidx, GTSIM, SCORE, BBOX, TBOX, ROWSUM, CLS);
  k_rankgather<<<BQ, 256, 0, stream>>>(SCORE, BBOX, CLS, bidx, ORDER, SB, BSTART, CNT, LIST);
  k_sel2<<<NN, 256, 0, stream>>>(S2T, SEL2);
  k_pack<<<PB_SIMT + PB_OMT + PB_TMT + PB_GTP, 256, 0, stream>>>(
      SIMS, pm, tm, GTSIM, SEL2, BSTART, SIMTB, OMT, TMT, GTP, MSUM, SC);
  k_cellnms<<<(BB*CC + 255)/256, 256, 0, stream>>>(SB, CNT, LIST, KEEPF);
  k_compact<<<1, 256, 0, stream>>>(KEEPF, ORDER, SB, NMSIDX, KB, KINT);
  k_gtsel<<<BQ, 512, 0, stream>>>(KB, TBOX, NMSIDX, pl, KINT, GSEL, OE);
  k_m_t<<<dim3(10, 10), 256, 0, stream>>>(te, OE, MM);
  k_ce<<<NN, 64, 0, stream>>>(MM, SC);
  k_zsoft<<<dim3((WHX/64) * BB), 256, 0, stream>>>(SIMTB, OMT, GTP, TMT, BSTART, SC);
  k_final3<<<1, 512, 0, stream>>>(GSEL, TBOX, bidx, ROWSUM, MSUM, SC, KINT, out);
}

// Round 17
// 232.953 us; speedup vs baseline: 1.4398x; 1.0298x over previous
//
#include <hip/hip_runtime.h>
#include <stdint.h>

#define DEVFN __device__ __forceinline__

typedef unsigned short u16;
typedef short bf16x8 __attribute__((ext_vector_type(8)));
typedef float f32x4 __attribute__((ext_vector_type(4)));

constexpr int BB = 8, QQ = 300, CC = 300, NN = 300, DD = 256;
constexpr int WHX = 9216, BQ = 2400, SIMW = 600;
constexpr int QP = 320;
constexpr int CP = 304;   // padded C rows (19 MFMA tiles; rows 300..303 zero)
constexpr int KP = 96;
constexpr int NP = 416;
constexpr int CELLCAP = 300;

// ---------------- workspace layout (float units) ----------------
constexpr size_t F_SIMS   = 0;
constexpr size_t F_GTSIM  = F_SIMS   + (size_t)BQ*SIMW;
constexpr size_t F_MM     = F_GTSIM  + (size_t)NN*CC;
constexpr size_t F_SCORE  = F_MM     + (size_t)NN*NN;
constexpr size_t F_BBOX   = F_SCORE  + BQ;
constexpr size_t F_TB     = F_BBOX   + (size_t)BQ*4;
constexpr size_t F_SB     = F_TB     + (size_t)NN*4;
constexpr size_t F_SAREA  = F_SB     + (size_t)BQ*4;
constexpr size_t F_KB     = F_SAREA  + BQ;
constexpr size_t F_ROWSUM = F_KB     + (size_t)BQ*4;
constexpr size_t F_OE     = F_ROWSUM + NN;                     // ---- zeroed zone
constexpr size_t F_GSEL   = F_OE     + (size_t)NN*DD;
constexpr size_t F_MSUM   = F_GSEL   + (size_t)NN*4;
constexpr size_t F_STGT   = F_MSUM   + NN;
constexpr size_t F_SC     = F_STGT   + 8;
constexpr size_t F_CNT    = F_SC     + 16;
constexpr size_t F_ACCEND = F_CNT    + BQ;                     // ---- end zeroed zone
constexpr size_t F_ORDER  = F_ACCEND;
constexpr size_t F_NMSIDX = F_ORDER  + BQ;
constexpr size_t F_SEL2   = F_NMSIDX + BQ;
constexpr size_t F_BSTART = F_SEL2   + NN;
constexpr size_t F_KINT   = F_BSTART + 16;
constexpr size_t F_CLS    = F_KINT   + 4;
constexpr size_t F_KEEPF  = F_CLS    + BQ;
constexpr size_t F_LIST   = F_KEEPF  + BQ;
constexpr size_t F_S2T    = F_LIST   + (size_t)BQ*CELLCAP;     // f32 [300][2400]
constexpr size_t F_SIMTB  = ((F_S2T + (size_t)NN*BQ + 7) & ~(size_t)7);  // u16[8][304][320]
constexpr size_t F_OMT    = F_SIMTB + (size_t)BB*CP*QP/2;
constexpr size_t F_TMT    = F_OMT   + (size_t)WHX*QP/2;
constexpr size_t F_GTP    = F_TMT   + (size_t)WHX*NP/2;        // u16[8][304][96]
constexpr size_t F_TOTAL  = F_GTP   + (size_t)BB*CP*KP/2;

// ---------------- JAX threefry2x32 (partitionable scheme) ----------------
DEVFN uint32_t rotl32(uint32_t v, int r){ return (v << r) | (v >> (32 - r)); }

DEVFN void tf2x32(uint32_t k0, uint32_t k1, uint32_t x0, uint32_t x1,
                  uint32_t& o0, uint32_t& o1){
  uint32_t ks2 = k0 ^ k1 ^ 0x1BD11BDAu;
  x0 += k0; x1 += k1;
#define TFR(r) x0 += x1; x1 = rotl32(x1, r); x1 ^= x0;
  TFR(13) TFR(15) TFR(26) TFR(6)   x0 += k1;  x1 += ks2 + 1u;
  TFR(17) TFR(29) TFR(16) TFR(24)  x0 += ks2; x1 += k0  + 2u;
  TFR(13) TFR(15) TFR(26) TFR(6)   x0 += k0;  x1 += k1  + 3u;
  TFR(17) TFR(29) TFR(16) TFR(24)  x0 += k1;  x1 += ks2 + 4u;
  TFR(13) TFR(15) TFR(26) TFR(6)   x0 += ks2; x1 += k0  + 5u;
#undef TFR
  o0 = x0; o1 = x1;
}

DEVFN void subkey(int i, uint32_t& k0, uint32_t& k1){
  tf2x32(0u, 42u, 0u, (uint32_t)i, k0, k1);
}

DEVFN float gumbel32(uint32_t k0, uint32_t k1, uint32_t idx){
  uint32_t h, l; tf2x32(k0, k1, 0u, idx, h, l);
  uint32_t bits = h ^ l;
  float f = __uint_as_float((bits >> 9) | 0x3F800000u) - 1.0f;
  const float tiny = 1.17549435e-38f;
  float u = fmaxf(tiny, f + tiny);
  return -logf(-logf(u));
}

DEVFN float iou_xyxy(float ax1,float ay1,float ax2,float ay2,
                     float bx1,float by1,float bx2,float by2){
  float aa = (ax2-ax1)*(ay2-ay1);
  float ab = (bx2-bx1)*(by2-by1);
  float lx = fmaxf(ax1,bx1), ly = fmaxf(ay1,by1);
  float rx = fminf(ax2,bx2), ry = fminf(ay2,by2);
  float iw = fmaxf(rx-lx,0.f), ih = fmaxf(ry-ly,0.f);
  float in_ = iw*ih;
  return in_/(aa+ab-in_);
}

DEVFN u16 f2bf(float x){
  uint32_t u = __float_as_uint(x);
  uint32_t r = u + 0x7FFFu + ((u >> 16) & 1u);
  return (u16)(r >> 16);
}

DEVFN void gload_lds16(const u16* g, u16* l){
  __builtin_amdgcn_global_load_lds(
      (const __attribute__((address_space(1))) unsigned int*)g,
      (__attribute__((address_space(3))) unsigned int*)l,
      16, 0, 0);
}

// ---------------- K1: tiled f32 GEMM 64x64 + s2T side-write ----------------
__global__ __launch_bounds__(256) void k_gemm_t(
    const float* __restrict__ pl, const float* __restrict__ ce,
    const float* __restrict__ te, float* __restrict__ sims,
    float* __restrict__ gtsim, float* __restrict__ s2t){
  __shared__ float As[16][64];
  __shared__ float Bs[16][64];
  const int row0 = blockIdx.x * 64, col0 = blockIdx.y * 64;
  const int tid = threadIdx.x;
  const int lrow = tid >> 2, lk0 = (tid & 3) * 4;
  const int tr = tid >> 4, tc = tid & 15;

  float acc[4][4];
  #pragma unroll
  for (int i = 0; i < 4; i++)
    #pragma unroll
    for (int j = 0; j < 4; j++) acc[i][j] = 0.f;

  const float4 z4 = {0.f,0.f,0.f,0.f};
  const int grow = row0 + lrow;
  const int gcol = col0 + lrow;
  const float* arow = nullptr;
  if (grow < 2400) arow = pl + (size_t)grow * DD;
  else if (grow < 2700) arow = te + (size_t)(grow - 2400) * DD;
  const float* brow = nullptr;
  if (gcol < 300) brow = ce + (size_t)gcol * DD;
  else if (gcol < 600) brow = te + (size_t)(gcol - 300) * DD;

  float4 av = arow ? *(const float4*)(arow + lk0) : z4;
  float4 bv = brow ? *(const float4*)(brow + lk0) : z4;

  for (int step = 0; step < 16; step++){
    __syncthreads();
    #pragma unroll
    for (int j = 0; j < 4; j++){
      As[lk0 + j][lrow] = ((const float*)&av)[j];
      Bs[lk0 + j][lrow] = ((const float*)&bv)[j];
    }
    __syncthreads();
    if (step + 1 < 16){
      const int k0 = (step + 1) * 16;
      av = arow ? *(const float4*)(arow + k0 + lk0) : z4;
      bv = brow ? *(const float4*)(brow + k0 + lk0) : z4;
    }
    #pragma unroll
    for (int kk = 0; kk < 16; kk++){
      float4 a4 = *(const float4*)&As[kk][tr*4];
      float4 b4 = *(const float4*)&Bs[kk][tc*4];
      float a[4] = {a4.x,a4.y,a4.z,a4.w};
      float b[4] = {b4.x,b4.y,b4.z,b4.w};
      #pragma unroll
      for (int i = 0; i < 4; i++)
        #pragma unroll
        for (int j = 0; j < 4; j++)
          acc[i][j] = fmaf(a[i], b[j], acc[i][j]);
    }
  }

  #pragma unroll
  for (int i = 0; i < 4; i++){
    const int r = row0 + tr*4 + i;
    const int c0 = col0 + tc*4;
    if (r < 2400){
      if (c0 < 600){
        float4 o0 = {acc[i][0],acc[i][1],acc[i][2],acc[i][3]};
        *(float4*)(sims + (size_t)r*SIMW + c0) = o0;
        if (c0 >= 300){
          #pragma unroll
          for (int j = 0; j < 4; j++)
            s2t[(size_t)(c0 + j - 300)*BQ + r] = acc[i][j];
        }
      }
    } else if (r < 2700){
      const int n = r - 2400;
      #pragma unroll
      for (int j = 0; j < 4; j++){
        int c = c0 + j;
        if (c < 300) gtsim[(size_t)n*CC + c] = acc[i][j];
      }
    }
  }
}

// ---------------- K2: per-bq scores/argmax(g0)/boxes/cls; tb rows; gtsim rowsums ----------------
// One wave per bq; 5 elems/lane; all reductions via shfl (no barriers).
// Max/argmax (lowest-index tie-break) are exact; rowsum order differs (harmless).
__global__ __launch_bounds__(64) void k_post(
    const float* __restrict__ sims, const float* __restrict__ pb,
    const float* __restrict__ tbb, const int* __restrict__ tids,
    const int* __restrict__ bidx, const float* __restrict__ gtsim,
    float* __restrict__ score, float* __restrict__ bbox,
    float* __restrict__ tb, float* __restrict__ rowsum,
    int* __restrict__ clsout){
  const int bq = blockIdx.x;
  const int lane = threadIdx.x;
  float v[5];
  #pragma unroll
  for (int k = 0; k < 5; k++){
    int c = lane + 64*k;
    v[k] = (c < CC) ? sims[(size_t)bq*SIMW + c] : -INFINITY;
  }
  float mx = v[0];
  #pragma unroll
  for (int k = 1; k < 5; k++) mx = fmaxf(mx, v[k]);
  #pragma unroll
  for (int o = 1; o < 64; o <<= 1) mx = fmaxf(mx, __shfl_xor(mx, o));
  if (lane == 0) score[bq] = mx;

  uint32_t gk0, gk1; subkey(0, gk0, gk1);
  float besty = -INFINITY; int besti = 0x7fffffff;
  #pragma unroll
  for (int k = 0; k < 5; k++){
    int c = lane + 64*k;
    if (c < CC){
      float y = v[k] + gumbel32(gk0, gk1, (uint32_t)(bq*CC + c));
      if (y > besty || (y == besty && c < besti)){ besty = y; besti = c; }
    }
  }
  #pragma unroll
  for (int o = 1; o < 64; o <<= 1){
    float oy = __shfl_xor(besty, o);
    int   oi = __shfl_xor(besti, o);
    if (oy > besty || (oy == besty && oi < besti)){ besty = oy; besti = oi; }
  }
  if (lane == 0){
    int cls = besti;
    clsout[bq] = cls;
    float ox = 224.0f * (float)cls;
    float oy2 = 224.0f * (float)(bq / QQ);
    float cx = pb[bq*4+0], cy = pb[bq*4+1], ww = pb[bq*4+2], hh = pb[bq*4+3];
    bbox[bq*4+0] = cx - 0.5f*ww + ox;
    bbox[bq*4+1] = cy - 0.5f*hh + oy2;
    bbox[bq*4+2] = cx + 0.5f*ww + ox;
    bbox[bq*4+3] = cy + 0.5f*hh + oy2;
  }
  if (bq < NN){
    float rs = 0.f;
    #pragma unroll
    for (int k = 0; k < 5; k++){
      int c = lane + 64*k;
      if (c < CC) rs += gtsim[(size_t)bq*CC + c];
    }
    #pragma unroll
    for (int o = 1; o < 64; o <<= 1) rs += __shfl_xor(rs, o);
    if (lane == 0) rowsum[bq] = rs;
    if (lane == 1){
      float gx = 224.0f * (float)tids[bq], gy = 224.0f * (float)bidx[bq];
      float cx = tbb[bq*4+0], cy = tbb[bq*4+1], ww = tbb[bq*4+2], hh = tbb[bq*4+3];
      tb[bq*4+0] = cx - 0.5f*ww + gx;
      tb[bq*4+1] = cy - 0.5f*hh + gy;
      tb[bq*4+2] = cx + 0.5f*ww + gx;
      tb[bq*4+3] = cy + 0.5f*hh + gy;
    }
  }
}

// ---------------- K3: fused rank + gather + bucket (wave-reduce + 1 barrier) ----------------
__global__ __launch_bounds__(256) void k_rankgather(
    const float* __restrict__ score, const float* __restrict__ bbox,
    const int* __restrict__ cls, const int* __restrict__ bidx,
    int* __restrict__ order, float* __restrict__ sb,
    int* __restrict__ bstart, int* __restrict__ cnt,
    int* __restrict__ list){
  const int t = blockIdx.x;
  const int tid = threadIdx.x;
  const float st = score[t];
  int c = 0;
  for (int j = tid; j < BQ; j += 256){
    float sj = score[j];
    c += (sj > st) || (sj == st && j < t);
  }
  #pragma unroll
  for (int o = 1; o < 64; o <<= 1) c += __shfl_xor(c, o);
  __shared__ int wsum[4];
  if ((tid & 63) == 0) wsum[tid >> 6] = c;
  __syncthreads();
  if (tid == 0){
    int r = wsum[0] + wsum[1] + wsum[2] + wsum[3];
    order[r] = t;
    float x1 = bbox[t*4+0], y1 = bbox[t*4+1], x2 = bbox[t*4+2], y2 = bbox[t*4+3];
    sb[r*4+0] = x1; sb[r*4+1] = y1; sb[r*4+2] = x2; sb[r*4+3] = y2;
    int key = (t / QQ) * CC + cls[t];
    int slot = atomicAdd(&cnt[key], 1);
    list[(size_t)key*CELLCAP + slot] = r;
  }
  if (t == 0 && tid >= 32 && tid < 41){
    int b = tid - 32, cb = 0;
    for (int n = 0; n < NN; n++) cb += (bidx[n] < b);
    bstart[b] = cb;
  }
}

// ---------------- K6': per-cell greedy NMS ----------------
__global__ __launch_bounds__(256) void k_cellnms(
    const float* __restrict__ sb, const int* __restrict__ cnt,
    const int* __restrict__ list, int* __restrict__ keepf){
  int key = blockIdx.x*256 + threadIdx.x;
  if (key >= BB*CC) return;
  int m = cnt[key];
  if (m <= 0) return;
  const int* lst = list + (size_t)key*CELLCAP;
  unsigned long long keptmask = 0ull;
  int prevp = -1;
  for (int a = 0; a < m; a++){
    int pa = 0x7fffffff;
    for (int j = 0; j < m; j++){
      int pj = lst[j];
      if (pj > prevp && pj < pa) pa = pj;
    }
    prevp = pa;
    float4 A = ((const float4*)sb)[pa];
    float areaA = (A.z-A.x)*(A.w-A.y);
    bool kept = true;
    int pbprev = -1;
    for (int b2 = 0; b2 < a; b2++){
      int pb = 0x7fffffff;
      for (int j = 0; j < m; j++){
        int pj = lst[j];
        if (pj > pbprev && pj < pb) pb = pj;
      }
      pbprev = pb;
      bool keptb = (m <= 64) ? (((keptmask >> b2) & 1ull) != 0ull) : (keepf[pb] != 0);
      if (!keptb) continue;
      float4 B = ((const float4*)sb)[pb];
      float areaB = (B.z-B.x)*(B.w-B.y);
      float lx = fmaxf(A.x,B.x), ly = fmaxf(A.y,B.y);
      float rx = fminf(A.z,B.z), ry = fminf(A.w,B.w);
      float iw = fmaxf(rx-lx,0.f), ih = fmaxf(ry-ly,0.f);
      float inter = iw*ih;
      if (inter/(areaA + areaB - inter) > 0.5f){ kept = false; break; }
    }
    if (m <= 64 && kept) keptmask |= (1ull << a);
    keepf[pa] = kept ? 1 : 0;
  }
}

// ---------------- K7: compact ----------------
__global__ __launch_bounds__(256) void k_compact(
    const int* __restrict__ keepflag, const int* __restrict__ order,
    const float* __restrict__ sb, int* __restrict__ nmsidx,
    float* __restrict__ kb, int* __restrict__ kint){
  __shared__ int csum[256];
  int tid = threadIdx.x;
  int p0 = tid*10;
  int keepf[10];
  int cnt = 0;
  #pragma unroll
  for (int d = 0; d < 10; d++){
    int p = p0 + d;
    int k = 0;
    if (p < BQ) k = keepflag[p];
    keepf[d] = k; cnt += k;
  }
  csum[tid] = cnt; __syncthreads();
  for (int s = 1; s < 256; s <<= 1){
    int add = (tid >= s) ? csum[tid - s] : 0;
    __syncthreads();
    csum[tid] += add;
    __syncthreads();
  }
  int pos = csum[tid] - cnt;
  #pragma unroll
  for (int d = 0; d < 10; d++){
    if (keepf[d]){
      int p = p0 + d;
      nmsidx[pos] = order[p];
      ((float4*)kb)[pos] = ((const float4*)sb)[p];
      pos++;
    }
  }
  if (tid == 255) kint[0] = csum[255];
}

// ---------------- K8: per-kept-box scatter (one wave, shfl reductions) ----------------
__global__ __launch_bounds__(64) void k_gtsel(
    const float* __restrict__ kb, const float* __restrict__ tb,
    const int* __restrict__ nmsidx, const float* __restrict__ pl,
    const int* __restrict__ kint, float* __restrict__ gsel,
    float* __restrict__ oe){
  const int k = blockIdx.x;
  if (k >= kint[0]) return;
  const int lane = threadIdx.x;
  float4 a = ((const float4*)kb)[k];
  float iou[5];
  float mx = -INFINITY;
  #pragma unroll
  for (int j = 0; j < 5; j++){
    int n = lane + 64*j;
    if (n < NN){
      float4 t = ((const float4*)tb)[n];
      float u = iou_xyxy(a.x,a.y,a.z,a.w, t.x,t.y,t.z,t.w);
      if (u != u) u = 0.f;
      iou[j] = u;
      mx = fmaxf(mx, u);
    } else iou[j] = -INFINITY;
  }
  #pragma unroll
  for (int o = 1; o < 64; o <<= 1) mx = fmaxf(mx, __shfl_xor(mx, o));
  float e[5];
  float ssum = 0.f;
  #pragma unroll
  for (int j = 0; j < 5; j++){
    int n = lane + 64*j;
    e[j] = (n < NN) ? expf(iou[j] - mx) : 0.f;
    ssum += e[j];
  }
  #pragma unroll
  for (int o = 1; o < 64; o <<= 1) ssum += __shfl_xor(ssum, o);
  uint32_t gk0, gk1; subkey(1, gk0, gk1);
  float besty = -INFINITY; int besti = 0x7fffffff;
  #pragma unroll
  for (int j = 0; j < 5; j++){
    int n = lane + 64*j;
    if (n < NN){
      float y = e[j] / ssum + gumbel32(gk0, gk1, (uint32_t)(k*NN + n));
      if (y > besty || (y == besty && n < besti)){ besty = y; besti = n; }
    }
  }
  #pragma unroll
  for (int o = 1; o < 64; o <<= 1){
    float oy = __shfl_xor(besty, o);
    int   oi = __shfl_xor(besti, o);
    if (oy > besty || (oy == besty && oi < besti)){ besty = oy; besti = oi; }
  }
  const int sel = besti;
  if (lane < 4) atomicAdd(&gsel[sel*4 + lane], ((const float*)&a)[lane]);
  const float* plrow = pl + (size_t)nmsidx[k]*DD;
  #pragma unroll
  for (int j = 0; j < 4; j++){
    int c = lane + 64*j;
    atomicAdd(&oe[(size_t)sel*DD + c], plrow[c]);
  }
}

// ---------------- K10: tiled M = te @ oe^T (32x32 tiles) ----------------
__global__ __launch_bounds__(256) void k_m_t(
    const float* __restrict__ te, const float* __restrict__ oe,
    float* __restrict__ M){
  __shared__ float As[16][32];
  __shared__ float Bs[16][32];
  const int row0 = blockIdx.x * 32, col0 = blockIdx.y * 32;
  const int tid = threadIdx.x;
  const int lr = tid >> 3, lk0 = (tid & 7) * 2;
  const int tr = tid >> 4, tc = tid & 15;
  float acc[2][2] = {{0.f,0.f},{0.f,0.f}};
  const float* arow = (row0 + lr < NN) ? te + (size_t)(row0 + lr)*DD : nullptr;
  const float* brow = (col0 + lr < NN) ? oe + (size_t)(col0 + lr)*DD : nullptr;
  for (int step = 0; step < 16; step++){
    const int k0 = step*16;
    float2 a2 = arow ? *(const float2*)(arow + k0 + lk0) : float2{0.f,0.f};
    float2 b2 = brow ? *(const float2*)(brow + k0 + lk0) : float2{0.f,0.f};
    __syncthreads();
    As[lk0][lr] = a2.x; As[lk0+1][lr] = a2.y;
    Bs[lk0][lr] = b2.x; Bs[lk0+1][lr] = b2.y;
    __syncthreads();
    #pragma unroll
    for (int kk = 0; kk < 16; kk++){
      float a0 = As[kk][tr*2], a1 = As[kk][tr*2+1];
      float b0 = Bs[kk][tc*2], b1 = Bs[kk][tc*2+1];
      acc[0][0] = fmaf(a0,b0,acc[0][0]);
      acc[0][1] = fmaf(a0,b1,acc[0][1]);
      acc[1][0] = fmaf(a1,b0,acc[1][0]);
      acc[1][1] = fmaf(a1,b1,acc[1][1]);
    }
  }
  #pragma unroll
  for (int i = 0; i < 2; i++){
    int r = row0 + tr*2 + i;
    if (r >= NN) continue;
    #pragma unroll
    for (int j = 0; j < 2; j++){
      int c = col0 + tc*2 + j;
      if (c < NN) M[(size_t)r*NN + c] = acc[i][j];
    }
  }
}

// ---------------- K11: both cross-entropies ----------------
__global__ __launch_bounds__(64) void k_ce(
    const float* __restrict__ M, float* __restrict__ sc){
  int i = blockIdx.x, lane = threadIdx.x;
  float m = -INFINITY;
  for (int j = lane; j < NN; j += 64) m = fmaxf(m, M[(size_t)i*NN + j]);
  for (int o = 32; o > 0; o >>= 1) m = fmaxf(m, __shfl_xor(m, o));
  float s = 0.f;
  for (int j = lane; j < NN; j += 64) s += expf(M[(size_t)i*NN + j] - m);
  for (int o = 32; o > 0; o >>= 1) s += __shfl_xor(s, o);
  float lr = m + logf(s);
  float m2 = -INFINITY;
  for (int j = lane; j < NN; j += 64) m2 = fmaxf(m2, M[(size_t)j*NN + i]);
  for (int o = 32; o > 0; o >>= 1) m2 = fmaxf(m2, __shfl_xor(m2, o));
  float s2 = 0.f;
  for (int j = lane; j < NN; j += 64) s2 += expf(M[(size_t)j*NN + i] - m2);
  for (int o = 32; o > 0; o >>= 1) s2 += __shfl_xor(s2, o);
  float lc = m2 + logf(s2);
  if (lane == 0){
    float d = M[(size_t)i*NN + i];
    atomicAdd(&sc[0], lr - d);
    atomicAdd(&sc[1], lc - d);
  }
}

// ---------------- K12: sel2 (coalesced via s2T) ----------------
__global__ __launch_bounds__(256) void k_sel2(
    const float* __restrict__ s2t, int* __restrict__ sel2){
  int n = blockIdx.x, tid = threadIdx.x;
  uint32_t gk0, gk1; subkey(2, gk0, gk1);
  float best = -INFINITY; int bi = 0x7fffffff;
  for (int r = tid; r < BQ; r += 256){
    float v = s2t[(size_t)n*BQ + r] + gumbel32(gk0, gk1, (uint32_t)(r*NN + n));
    if (v > best){ best = v; bi = r; }
  }
  __shared__ float sv[256];
  __shared__ int   si[256];
  sv[tid] = best; si[tid] = bi; __syncthreads();
  for (int s = 128; s > 0; s >>= 1){
    if (tid < s){
      float ov = sv[tid+s]; int oi = si[tid+s];
      if (ov > sv[tid] || (ov == sv[tid] && oi < si[tid])){ sv[tid] = ov; si[tid] = oi; }
    }
    __syncthreads();
  }
  if (tid == 0) sel2[n] = si[0];
}

// ---------------- K_PACK: fused transposes + om-loss (4 ranges; OM fused into OMT) ----------------
constexpr int PB_SIMT = 400;                // (10 q) x (5 c) x 8 b
constexpr int PB_OMT  = 1440;               // (10 q) x 144 wh  (also computes om-loss + masksum)
constexpr int PB_TMT  = 1872;               // (13 n) x 144 wh
constexpr int PB_GTP  = 114;                // 8*304*12 / 256
__global__ __launch_bounds__(256) void k_pack(
    const float* __restrict__ sims, const float* __restrict__ pm,
    const float* __restrict__ tm, const float* __restrict__ gtsim,
    const int* __restrict__ sel2, const int* __restrict__ bstart,
    u16* __restrict__ simTb, u16* __restrict__ omT,
    u16* __restrict__ tmT, u16* __restrict__ gtp,
    float* __restrict__ msum, float* __restrict__ sc){
  __shared__ float ld[32][65];
  __shared__ float sm_ts[32];
  __shared__ float sm_d2;
  const int blk = blockIdx.x;
  const int tid = threadIdx.x;

  if (blk < PB_SIMT){
    int bx = blk % 10, by = (blk / 10) % 5, b = blk / 50;
    int q0 = bx*32, c0 = by*64;
    for (int i = tid; i < 32*64; i += 256){
      int qi = i >> 6, ci = i & 63;
      int q = q0 + qi, c = c0 + ci;
      ld[qi][ci] = (q < QQ && c < CC) ? sims[((size_t)b*QQ + q)*SIMW + c] : 0.f;
    }
    __syncthreads();
    int cloc = tid >> 2, j0 = (tid & 3)*8;
    int c = c0 + cloc;
    if (c < CP){
      u16 tmp[8];
      #pragma unroll
      for (int j = 0; j < 8; j++) tmp[j] = f2bf(ld[j0+j][cloc]);
      *(uint4*)(simTb + ((size_t)b*CP + c)*QP + q0 + j0) = *(const uint4*)tmp;
    }
  } else if (blk < PB_SIMT + PB_OMT){
    // OMT transpose + fused overall-mask-loss / masksum (raw pm, scale at write)
    int r = blk - PB_SIMT;
    int q0 = (r % 10)*32, wh0 = (r / 10)*64;
    if (tid < 32) sm_ts[tid] = 0.f;
    if (tid == 32) sm_d2 = 0.f;
    __syncthreads();
    float d2loc = 0.f;
    for (int i = tid; i < 32*64; i += 256){
      int qi = i >> 6, wi = i & 63;
      int q = q0 + qi;
      float pv = 0.f;
      if (q < QQ){
        pv = pm[(size_t)sel2[q]*WHX + wh0 + wi];
        float tv = tm[(size_t)q*WHX + wh0 + wi];
        float d = pv - tv;
        d2loc += d*d;
        atomicAdd(&sm_ts[qi], tv);
      }
      ld[qi][wi] = pv;
    }
    atomicAdd(&sm_d2, d2loc);
    __syncthreads();
    int wloc = tid >> 2, j0 = (tid & 3)*8;
    u16 tmp[8];
    #pragma unroll
    for (int j = 0; j < 8; j++) tmp[j] = f2bf(ld[j0+j][wloc] * (1.0f/96.0f));
    *(uint4*)(omT + (size_t)(wh0+wloc)*QP + q0 + j0) = *(const uint4*)tmp;
    if (tid < 32 && q0 + tid < NN) atomicAdd(&msum[q0 + tid], sm_ts[tid]);
    if (tid == 32) atomicAdd(&sc[2], sm_d2);
  } else if (blk < PB_SIMT + PB_OMT + PB_TMT){
    int r = blk - PB_SIMT - PB_OMT;
    int n0 = (r % 13)*32, wh0 = (r / 13)*64;
    for (int i = tid; i < 32*64; i += 256){
      int ni = i >> 6, wi = i & 63;
      int n = n0 + ni;
      ld[ni][wi] = (n < NN) ? tm[(size_t)n*WHX + wh0 + wi] : 0.f;
    }
    __syncthreads();
    int wloc = tid >> 2, j0 = (tid & 3)*8;
    u16 tmp[8];
    #pragma unroll
    for (int j = 0; j < 8; j++) tmp[j] = f2bf(ld[j0+j][wloc]);
    *(uint4*)(tmT + (size_t)(wh0+wloc)*NP + n0 + j0) = *(const uint4*)tmp;
  } else {
    int g = (blk - PB_SIMT - PB_OMT - PB_TMT)*256 + tid;
    int b = g / (CP*(KP/8));
    int rem = g - b*(CP*(KP/8));
    int c = rem / (KP/8);
    int kg = rem % (KP/8);
    int n0 = bstart[b], n1 = bstart[b+1];
    int kst = n0 & ~7;
    u16 tmp[8];
    #pragma unroll
    for (int j = 0; j < 8; j++){
      int n = kst + kg*8 + j;
      float v = (n >= n0 && n < n1 && c < CC) ? gtsim[(size_t)n*CC + c] : 0.f;
      tmp[j] = f2bf(v);
    }
    *(uint4*)(gtp + ((size_t)b*CP + c)*KP + kg*8) = *(const uint4*)tmp;
  }
}

// ---------------- K15: MFMA z-GEMM + column softmax + dice (round-14 form) ----------------
constexpr int ALDS = 32;
__global__ __launch_bounds__(256) void k_zsoft(
    const u16* __restrict__ simTb, const u16* __restrict__ omT,
    const u16* __restrict__ gtp, const u16* __restrict__ tmT,
    const int* __restrict__ bstart, float* __restrict__ sc){
  const int bid = blockIdx.x;
  const int xcd = bid & 7;
  const int r9  = bid >> 3;
  const int tile = xcd * 18 + (r9 % 18);
  const int b    = r9 / 18;
  const int tid = threadIdx.x;
  const int w = tid >> 6, l = tid & 63;
  const int lrow = l & 15, lgrp = l >> 4;
  const int col = tile*64 + w*16 + lrow;

  __shared__ u16 As[2][CP*ALDS];
  __shared__ float red[256];

  const u16* Ab = simTb + (size_t)b*CP*QP;
  int srcoff[5];
  #pragma unroll
  for (int i = 0; i < 5; i++){
    int p = (w*5 + i)*64 + l;
    int row = p >> 2, cs = p & 3;
    int g = cs ^ ((row >> 1) & 3);
    srcoff[i] = row*QP + g*8;
  }
  const int nIss = (w == 3) ? 4 : 5;
  const int roff = (lgrp ^ ((lrow >> 1) & 3)) << 3;
  const u16* pB = omT + (size_t)col*QP + lgrp*8;

  #pragma unroll
  for (int i = 0; i < 5; i++){
    if (i < nIss) gload_lds16(Ab + srcoff[i], &As[0][(w*5+i)*512]);
  }
  bf16x8 bcur = *(const bf16x8*)(pB);

  f32x4 acc[19];
  #pragma unroll
  for (int t = 0; t < 19; t++) acc[t] = (f32x4){0.f,0.f,0.f,0.f};
  __syncthreads();

  for (int ks = 0; ks < 10; ks++){
    const int cur = ks & 1;
    bf16x8 bnext;
    if (ks + 1 < 10){
      const int ko = (ks + 1) * 32;
      #pragma unroll
      for (int i = 0; i < 5; i++){
        if (i < nIss) gload_lds16(Ab + srcoff[i] + ko, &As[cur ^ 1][(w*5+i)*512]);
      }
      bnext = *(const bf16x8*)(pB + ko);
    }
    __builtin_amdgcn_s_setprio(1);
    #pragma unroll
    for (int t = 0; t < 19; t++){
      bf16x8 af = *(const bf16x8*)&As[cur][t*16*ALDS + lrow*ALDS + roff];
      acc[t] = __builtin_amdgcn_mfma_f32_16x16x32_bf16(af, bcur, acc[t], 0, 0, 0);
    }
    __builtin_amdgcn_s_setprio(0);
    bcur = bnext;
    __syncthreads();
  }

  float lmax = -INFINITY;
  #pragma unroll
  for (int t = 0; t < 19; t++){
    if (t == 18 && lgrp == 3) continue;
    lmax = fmaxf(lmax, fmaxf(fmaxf(acc[t][0], acc[t][1]), fmaxf(acc[t][2], acc[t][3])));
  }
  lmax = fmaxf(lmax, __shfl_xor(lmax, 16));
  lmax = fmaxf(lmax, __shfl_xor(lmax, 32));
  float ls = 0.f;
  #pragma unroll
  for (int t = 0; t < 19; t++){
    if (t == 18 && lgrp == 3){
      acc[t] = (f32x4){0.f,0.f,0.f,0.f};
      continue;
    }
    float p0 = __expf(acc[t][0] - lmax);
    float p1 = __expf(acc[t][1] - lmax);
    float p2 = __expf(acc[t][2] - lmax);
    float p3 = __expf(acc[t][3] - lmax);
    acc[t][0] = p0; acc[t][1] = p1; acc[t][2] = p2; acc[t][3] = p3;
    ls += p0 + p1 + p2 + p3;
  }
  float S = ls;
  S += __shfl_xor(S, 16);
  S += __shfl_xor(S, 32);
  float inv = 1.f / S;

  const int n0 = bstart[b];
  const int kst = n0 & ~7;
  const u16* tB = tmT + (size_t)col*NP + kst + lgrp*8;
  bf16x8 b2a = *(const bf16x8*)(tB);
  bf16x8 b2b = *(const bf16x8*)(tB + 32);
  bf16x8 b2c = *(const bf16x8*)(tB + 64);
  const u16* A2 = gtp + (size_t)b*CP*KP + (size_t)lrow*KP + lgrp*8;
  float dl = 0.f;
  #pragma unroll
  for (int t = 0; t < 19; t++){
    const u16* ar = A2 + (size_t)t*16*KP;
    f32x4 rr = (f32x4){0.f,0.f,0.f,0.f};
    rr = __builtin_amdgcn_mfma_f32_16x16x32_bf16(*(const bf16x8*)(ar),      b2a, rr, 0, 0, 0);
    rr = __builtin_amdgcn_mfma_f32_16x16x32_bf16(*(const bf16x8*)(ar + 32), b2b, rr, 0, 0, 0);
    rr = __builtin_amdgcn_mfma_f32_16x16x32_bf16(*(const bf16x8*)(ar + 64), b2c, rr, 0, 0, 0);
    dl += acc[t][0]*rr[0] + acc[t][1]*rr[1] + acc[t][2]*rr[2] + acc[t][3]*rr[3];
  }
  dl *= inv;

  red[tid] = dl; __syncthreads();
  for (int s = 128; s > 0; s >>= 1){
    if (tid < s) red[tid] += red[tid+s];
    __syncthreads();
  }
  if (tid == 0) atomicAdd(&sc[5], red[0]);
}

// ---------------- K16: fused gtiou + sumtgt + finalize ----------------
__global__ __launch_bounds__(512) void k_final3(
    const float* __restrict__ gsel, const float* __restrict__ tb,
    const int* __restrict__ bidx, const float* __restrict__ rowsum,
    const float* __restrict__ msum, const float* __restrict__ sc,
    const int* __restrict__ kint, float* __restrict__ out){
  int tid = threadIdx.x;
  __shared__ float s1[512], s2[512];
  __shared__ float stgt[8];
  if (tid < 8) stgt[tid] = 0.f;
  __syncthreads();
  float a1 = 0.f, a2 = 0.f;
  if (tid < NN){
    float4 g = ((const float4*)gsel)[tid];
    float4 t = ((const float4*)tb)[tid];
    float iou = iou_xyxy(g.x,g.y,g.z,g.w, t.x,t.y,t.z,t.w);
    a1 = 1.f - iou;
    a2 = fabsf(g.x-t.x) + fabsf(g.y-t.y) + fabsf(g.z-t.z) + fabsf(g.w-t.w);
    atomicAdd(&stgt[bidx[tid]], rowsum[tid] * msum[tid]);
  }
  s1[tid] = a1; s2[tid] = a2; __syncthreads();
  for (int s = 256; s > 0; s >>= 1){
    if (tid < s){ s1[tid] += s1[tid+s]; s2[tid] += s2[tid+s]; }
    __syncthreads();
  }
  if (tid == 0){
    float K = (float)kint[0];
    float cls = sc[0]/300.f + sc[1]/300.f;
    float stot = sc[5];
    float dice = 0.f;
    for (int b = 0; b < 8; b++) dice += stot / (9216.0f + stgt[b] + 1e-6f);
    dice *= (1.0f/8.0f);
    out[0] = cls;
    out[1] = dice;
    out[2] = (sc[2] / 2764800.0f) / K;
    out[3] = s1[0] / K;
    out[4] = s2[0] / K;
  }
}

// ---------------- launch ----------------
extern "C" void kernel_launch(void* const* d_in, const int* in_sizes, int n_in,
                              void* d_out, int out_size, void* d_ws, size_t ws_size,
                              hipStream_t stream) {
  const float* ce  = (const float*)d_in[0];
  const float* pl  = (const float*)d_in[1];
  const float* pb  = (const float*)d_in[2];
  const float* pm  = (const float*)d_in[3];
  const float* tm  = (const float*)d_in[4];
  const float* te  = (const float*)d_in[5];
  const float* tbb = (const float*)d_in[6];
  const int*  tids = (const int*)d_in[8];
  const int*  bidx = (const int*)d_in[9];
  float* out = (float*)d_out;
  float* w = (float*)d_ws;

  if (ws_size < F_TOTAL * sizeof(float)) return;

  float* SIMS   = w + F_SIMS;
  float* GTSIM  = w + F_GTSIM;
  float* MM     = w + F_MM;
  float* SCORE  = w + F_SCORE;
  float* BBOX   = w + F_BBOX;
  float* TBOX   = w + F_TB;
  float* SB     = w + F_SB;
  float* KB     = w + F_KB;
  float* ROWSUM = w + F_ROWSUM;
  float* OE     = w + F_OE;
  float* GSEL   = w + F_GSEL;
  float* MSUM   = w + F_MSUM;
  float* SC     = w + F_SC;
  float* S2T    = w + F_S2T;
  int*   CNT    = (int*)(w + F_CNT);
  int*   ORDER  = (int*)(w + F_ORDER);
  int*   NMSIDX = (int*)(w + F_NMSIDX);
  int*   SEL2   = (int*)(w + F_SEL2);
  int*   BSTART = (int*)(w + F_BSTART);
  int*   KINT   = (int*)(w + F_KINT);
  int*   CLS    = (int*)(w + F_CLS);
  int*   KEEPF  = (int*)(w + F_KEEPF);
  int*   LIST   = (int*)(w + F_LIST);
  u16* SIMTB = (u16*)(w + F_SIMTB);
  u16* OMT   = (u16*)(w + F_OMT);
  u16* TMT   = (u16*)(w + F_TMT);
  u16* GTP   = (u16*)(w + F_GTP);

  hipMemsetAsync(w + F_OE, 0, (F_ACCEND - F_OE) * sizeof(float), stream);

  k_gemm_t<<<dim3(43, 10), 256, 0, stream>>>(pl, ce, te, SIMS, GTSIM, S2T);
  k_post<<<BQ, 64, 0, stream>>>(SIMS, pb, tbb, tids, bidx, GTSIM, SCORE, BBOX, TBOX, ROWSUM, CLS);
  k_rankgather<<<BQ, 256, 0, stream>>>(SCORE, BBOX, CLS, bidx, ORDER, SB, BSTART, CNT, LIST);
  k_sel2<<<NN, 256, 0, stream>>>(S2T, SEL2);
  k_pack<<<PB_SIMT + PB_OMT + PB_TMT + PB_GTP, 256, 0, stream>>>(
      SIMS, pm, tm, GTSIM, SEL2, BSTART, SIMTB, OMT, TMT, GTP, MSUM, SC);
  k_cellnms<<<(BB*CC + 255)/256, 256, 0, stream>>>(SB, CNT, LIST, KEEPF);
  k_compact<<<1, 256, 0, stream>>>(KEEPF, ORDER, SB, NMSIDX, KB, KINT);
  k_gtsel<<<BQ, 64, 0, stream>>>(KB, TBOX, NMSIDX, pl, KINT, GSEL, OE);
  k_m_t<<<dim3(10, 10), 256, 0, stream>>>(te, OE, MM);
  k_ce<<<NN, 64, 0, stream>>>(MM, SC);
  k_zsoft<<<dim3((WHX/64) * BB), 256, 0, stream>>>(SIMTB, OMT, GTP, TMT, BSTART, SC);
  k_final3<<<1, 512, 0, stream>>>(GSEL, TBOX, bidx, ROWSUM, MSUM, SC, KINT, out);
}